// Round 2
// baseline (3010.333 us; speedup 1.0000x reference)
//
#include <hip/hip_runtime.h>
#include <hip/hip_bf16.h>

// ---------------------------------------------------------------------------
// VQ-VAE forward: quantize -> convT(32->128,s2) -> relu -> convT(128->64,s2)
//                 -> relu -> conv3x3(64->3) -> sigmoid
// fp32 compute; quantizer argmin in f64 (index flips vs reference are fatal).
// Workspace-adaptive batch chunking: x1/x2 sized per chunk from ws_size.
// ---------------------------------------------------------------------------

static constexpr int B_ = 32, C_ = 32, H_ = 64, W_ = 64, K_ = 1024;

// ---------------- prep: f64 codebook, ||e||^2, weight transposes -----------
// wt layout: [IC][jk(4)][parity pp(4)][OC], ky = 2j+py, kx = 2k+px
__global__ __launch_bounds__(256) void prep_kernel(
    const float* __restrict__ cb, const float* __restrict__ w1,
    const float* __restrict__ w2, double* __restrict__ cb64,
    double* __restrict__ e2, float* __restrict__ wt1, float* __restrict__ wt2) {
  int idx = blockIdx.x * 256 + threadIdx.x;
  if (idx < K_ * C_) cb64[idx] = (double)cb[idx];
  if (idx < K_) {
    double s = 0.0;
    #pragma unroll
    for (int c = 0; c < C_; ++c) { double v = (double)cb[idx * C_ + c]; s += v * v; }
    e2[idx] = s;
  }
  if (idx < 32 * 4 * 4 * 128) {  // wt1
    int o = idx & 127; int r = idx >> 7;
    int pp = r & 3; int jk = (r >> 2) & 3; int i = r >> 4;
    int py = pp >> 1, px = pp & 1, j = jk >> 1, k = jk & 1;
    wt1[idx] = w1[((i * 128 + o) * 4 + (2 * j + py)) * 4 + (2 * k + px)];
  }
  if (idx < 128 * 4 * 4 * 64) {  // wt2
    int o = idx & 63; int r = idx >> 6;
    int pp = r & 3; int jk = (r >> 2) & 3; int i = r >> 4;
    int py = pp >> 1, px = pp & 1, j = jk >> 1, k = jk & 1;
    wt2[idx] = w2[((i * 64 + o) * 4 + (2 * j + py)) * 4 + (2 * k + px)];
  }
}

// ---------------- quantize: idx[n] = argmin_k ||z_n - e_k||^2 (f64) --------
__global__ __launch_bounds__(256) void quant_kernel(
    const float* __restrict__ z, const double* __restrict__ cb64,
    const double* __restrict__ e2, int* __restrict__ qidx) {
  int n = blockIdx.x * 256 + threadIdx.x;  // 0..131071
  int b = n >> 12, hw = n & 4095;
  const float* zp = z + (((size_t)b * C_) << 12) + hw;
  double zr[C_];
  #pragma unroll
  for (int c = 0; c < C_; ++c) zr[c] = (double)zp[(size_t)c << 12];
  double best = -1e300; int bi = 0;
  for (int k = 0; k < K_; ++k) {
    const double* e = cb64 + k * C_;        // wave-uniform -> s_load
    double a0 = 0.0, a1 = 0.0, a2 = 0.0, a3 = 0.0;
    #pragma unroll
    for (int c = 0; c < C_; c += 4) {
      a0 += zr[c] * e[c];         a1 += zr[c + 1] * e[c + 1];
      a2 += zr[c + 2] * e[c + 2]; a3 += zr[c + 3] * e[c + 3];
    }
    double s = 2.0 * ((a0 + a1) + (a2 + a3)) - e2[k];
    if (s > best) { best = s; bi = k; }     // strict > == argmin-first on ties
  }
  qidx[n] = bi;
}

// ---------------- convT1 (32->128, k=4, s=2, SAME), input via qidx ---------
// out[b,o,y,x] = sum_{i,j,k} cb[idx[h,w], i] * W[i,o,2j+py,2k+px]
//   h = floor(y/2)-1+py+j (py = y&1); same for x. Wave owns one parity.
__global__ __launch_bounds__(256) void convt1_kernel(
    const int* __restrict__ qidx, const float* __restrict__ cb,
    const float* __restrict__ wt, const float* __restrict__ bias,
    float* __restrict__ y, int b0) {
  constexpr int IH = 64, IW = 64, OH = 128, OW = 128, OC = 128, OCH = 32;
  int b = blockIdx.z >> 2;
  int o0 = (blockIdx.z & 3) * OCH;
  int y0 = blockIdx.y * 8, x0 = blockIdx.x * 32;
  int tid = threadIdx.x, wid = tid >> 6, lane = tid & 63;
  int py = __builtin_amdgcn_readfirstlane((wid >> 1) & 1);
  int px = __builtin_amdgcn_readfirstlane(wid & 1);
  int ly = lane >> 4, lx = lane & 15;
  int yy = y0 + 2 * ly + py, xx = x0 + 2 * lx + px;
  int hbase = (y0 >> 1) - 1, wbase = (x0 >> 1) - 1;
  const int* ip = qidx + ((size_t)(b0 + b) << 12);

  __shared__ int lidx[6][18];
  __shared__ float lq[32][6][18];

  for (int t = tid; t < 108; t += 256) {
    int hloc = t / 18, wloc = t % 18;
    int hg = hbase + hloc, wg = wbase + wloc;
    lidx[hloc][wloc] = (hg >= 0 && hg < IH && wg >= 0 && wg < IW)
                           ? ip[hg * IW + wg] : -1;
  }
  __syncthreads();
  for (int t = tid; t < 32 * 108; t += 256) {
    int i = t / 108, r = t % 108, hloc = r / 18, wloc = r % 18;
    int id = lidx[hloc][wloc];
    lq[i][hloc][wloc] = (id >= 0) ? cb[id * 32 + i] : 0.f;
  }
  __syncthreads();

  float acc[OCH];
  #pragma unroll
  for (int o = 0; o < OCH; ++o) acc[o] = bias[o0 + o];
  int r0 = ly + py, c0 = lx + px;
  for (int i = 0; i < 32; ++i) {
    float t00 = lq[i][r0][c0],     t01 = lq[i][r0][c0 + 1];
    float t10 = lq[i][r0 + 1][c0], t11 = lq[i][r0 + 1][c0 + 1];
    const float* wp = wt + ((size_t)i * 16 + (py * 2 + px)) * OC + o0;
    #pragma unroll
    for (int o = 0; o < OCH; ++o) {
      acc[o] += t00 * wp[o] + t01 * wp[4 * OC + o] +
                t10 * wp[8 * OC + o] + t11 * wp[12 * OC + o];
    }
  }
  float* yp = y + (((size_t)b * OC + o0) * OH + yy) * OW + xx;
  #pragma unroll
  for (int o = 0; o < OCH; ++o)
    yp[(size_t)o * OH * OW] = fmaxf(acc[o], 0.f);
}

// ---------------- convT2 (128->64, k=4, s=2, SAME), dense input ------------
template <int IC, int OC, int IH, int IW>
__global__ __launch_bounds__(256) void convt_kernel(
    const float* __restrict__ x, const float* __restrict__ wt,
    const float* __restrict__ bias, float* __restrict__ y) {
  constexpr int OH = IH * 2, OW = IW * 2;
  constexpr int OCH = 32;
  int b = blockIdx.z / (OC / OCH);
  int o0 = (blockIdx.z % (OC / OCH)) * OCH;
  int y0 = blockIdx.y * 8, x0 = blockIdx.x * 32;
  int tid = threadIdx.x, wid = tid >> 6, lane = tid & 63;
  int py = __builtin_amdgcn_readfirstlane((wid >> 1) & 1);
  int px = __builtin_amdgcn_readfirstlane(wid & 1);
  int ly = lane >> 4, lx = lane & 15;
  int yy = y0 + 2 * ly + py, xx = x0 + 2 * lx + px;
  int hbase = (y0 >> 1) - 1, wbase = (x0 >> 1) - 1;

  __shared__ float lq[32][6][18];

  float acc[OCH];
  #pragma unroll
  for (int o = 0; o < OCH; ++o) acc[o] = bias[o0 + o];
  int r0 = ly + py, c0 = lx + px;

  for (int icb = 0; icb < IC; icb += 32) {
    __syncthreads();
    for (int t = tid; t < 32 * 108; t += 256) {
      int i = t / 108, r = t % 108, hloc = r / 18, wloc = r % 18;
      int hg = hbase + hloc, wg = wbase + wloc;
      float v = 0.f;
      if (hg >= 0 && hg < IH && wg >= 0 && wg < IW)
        v = x[(((size_t)b * IC + icb + i) * IH + hg) * IW + wg];
      lq[i][hloc][wloc] = v;
    }
    __syncthreads();
    for (int i = 0; i < 32; ++i) {
      float t00 = lq[i][r0][c0],     t01 = lq[i][r0][c0 + 1];
      float t10 = lq[i][r0 + 1][c0], t11 = lq[i][r0 + 1][c0 + 1];
      const float* wp = wt + ((size_t)(icb + i) * 16 + (py * 2 + px)) * OC + o0;
      #pragma unroll
      for (int o = 0; o < OCH; ++o) {
        acc[o] += t00 * wp[o] + t01 * wp[4 * OC + o] +
                  t10 * wp[8 * OC + o] + t11 * wp[12 * OC + o];
      }
    }
  }
  float* yp = y + (((size_t)b * OC + o0) * OH + yy) * OW + xx;
  #pragma unroll
  for (int o = 0; o < OCH; ++o)
    yp[(size_t)o * OH * OW] = fmaxf(acc[o], 0.f);
}

// ---------------- conv 3x3 (64->3) + sigmoid -------------------------------
__global__ __launch_bounds__(256) void conv3_kernel(
    const float* __restrict__ x, const float* __restrict__ w3,
    const float* __restrict__ b3, float* __restrict__ out) {
  constexpr int ICc = 64, N = 256;
  int b = blockIdx.z;
  int y0 = blockIdx.y * 8, x0 = blockIdx.x * 64;
  int tid = threadIdx.x;
  int ty = tid >> 5, tx = tid & 31;  // 8 rows x 32 col-pairs
  __shared__ float lx[16][10][67];
  float acc[3][2];
  #pragma unroll
  for (int o = 0; o < 3; ++o) { float bb = b3[o]; acc[o][0] = bb; acc[o][1] = bb; }
  int yy = y0 + ty, xx = x0 + tx * 2;
  for (int icb = 0; icb < ICc; icb += 16) {
    __syncthreads();
    for (int t = tid; t < 16 * 10 * 66; t += 256) {
      int wloc = t % 66; int r = t / 66; int hloc = r % 10; int i = r / 10;
      int hg = y0 - 1 + hloc, wg = x0 - 1 + wloc;
      float v = 0.f;
      if (hg >= 0 && hg < N && wg >= 0 && wg < N)
        v = x[(((size_t)b * ICc + icb + i) * N + hg) * N + wg];
      lx[i][hloc][wloc] = v;
    }
    __syncthreads();
    for (int i = 0; i < 16; ++i) {
      #pragma unroll
      for (int dy = 0; dy < 3; ++dy) {
        float t0 = lx[i][ty + dy][tx * 2],     t1 = lx[i][ty + dy][tx * 2 + 1];
        float t2 = lx[i][ty + dy][tx * 2 + 2], t3 = lx[i][ty + dy][tx * 2 + 3];
        #pragma unroll
        for (int o = 0; o < 3; ++o) {
          const float* w = w3 + (((size_t)o * ICc + icb + i) * 3 + dy) * 3;
          acc[o][0] += t0 * w[0] + t1 * w[1] + t2 * w[2];
          acc[o][1] += t1 * w[0] + t2 * w[1] + t3 * w[2];
        }
      }
    }
  }
  #pragma unroll
  for (int o = 0; o < 3; ++o) {
    float v0 = 1.f / (1.f + __expf(-acc[o][0]));
    float v1 = 1.f / (1.f + __expf(-acc[o][1]));
    float* op = out + (((size_t)b * 3 + o) * N + yy) * N + xx;
    op[0] = v0; op[1] = v1;
  }
}

// ---------------------------------------------------------------------------
extern "C" void kernel_launch(void* const* d_in, const int* in_sizes, int n_in,
                              void* d_out, int out_size, void* d_ws, size_t ws_size,
                              hipStream_t stream) {
  const float* z  = (const float*)d_in[0];
  const float* cb = (const float*)d_in[1];
  const float* w1 = (const float*)d_in[2];
  const float* b1 = (const float*)d_in[3];
  const float* w2 = (const float*)d_in[4];
  const float* b2 = (const float*)d_in[5];
  const float* w3 = (const float*)d_in[6];
  const float* b3 = (const float*)d_in[7];
  float* out = (float*)d_out;

  char* ws = (char*)d_ws;
  size_t off = 0;
  auto alloc = [&](size_t bytes) -> void* {
    void* p = (void*)(ws + off);
    off += (bytes + 255) & ~(size_t)255;
    return p;
  };
  double* cb64 = (double*)alloc((size_t)K_ * C_ * 8);         // 256 KB
  double* e2   = (double*)alloc((size_t)K_ * 8);              // 8 KB
  float*  wt1  = (float*)alloc((size_t)32 * 16 * 128 * 4);    // 256 KB
  float*  wt2  = (float*)alloc((size_t)128 * 16 * 64 * 4);    // 512 KB
  int*    qidx = (int*)alloc((size_t)B_ * H_ * W_ * 4);       // 512 KB
  size_t fixed = off;

  // per-batch-item intermediates: x1 [128,128,128], x2 [64,256,256]
  size_t per_b = ((size_t)128 * 128 * 128 + (size_t)64 * 256 * 256) * 4;
  long long avail = (long long)ws_size - (long long)fixed;
  int chunk = (avail >= (long long)per_b) ? (int)(avail / (long long)per_b) : 1;
  if (chunk > B_) chunk = B_;
  float* x1 = (float*)alloc((size_t)chunk * 128 * 128 * 128 * 4);
  float* x2 = (float*)alloc((size_t)chunk * 64 * 256 * 256 * 4);

  prep_kernel<<<512, 256, 0, stream>>>(cb, w1, w2, cb64, e2, wt1, wt2);
  quant_kernel<<<512, 256, 0, stream>>>(z, cb64, e2, qidx);

  for (int b0 = 0; b0 < B_; b0 += chunk) {
    int nb = (B_ - b0 < chunk) ? (B_ - b0) : chunk;
    dim3 g1(4, 16, nb * 4);   // OW/32, OH/8, nb * OC/32
    convt1_kernel<<<g1, 256, 0, stream>>>(qidx, cb, wt1, b1, x1, b0);
    dim3 g2(8, 32, nb * 2);
    convt_kernel<128, 64, 128, 128><<<g2, 256, 0, stream>>>(x1, wt2, b2, x2);
    dim3 g3(4, 32, nb);       // 256/64, 256/8, nb
    conv3_kernel<<<g3, 256, 0, stream>>>(x2, w3, b3, out + (size_t)b0 * 3 * 256 * 256);
  }
}

// Round 3
// 1027.917 us; speedup vs baseline: 2.9286x; 2.9286x over previous
//
#include <hip/hip_runtime.h>
#include <hip/hip_bf16.h>

// ---------------------------------------------------------------------------
// VQ-VAE forward, MFMA edition.
//   quantize (f64 argmin, exact) -> q bf16 [B][64][64][32] channel-last
//   convT1 32->128 s2 : MFMA 32x32x16, parity-decomposed implicit GEMM
//       -> x1 bf16 [B][4 parity][64][64][128]
//   convT2 128->64 s2 : same scheme -> x2 bf16 [B][4][128][128][64]
//   conv3 3x3 64->3 + sigmoid : MFMA 16x16x32 (N padded 3->16) -> out f32 NCHW
// Weights prepacked into MFMA B-fragment-linear bf16 at prep time (L2-resident,
// loaded global->VGPR per K-step). Input tiles staged in LDS as
// [k8][row][col][8] bf16 so A-fragment ds_read_b128 is conflict-free.
// ---------------------------------------------------------------------------

typedef __attribute__((ext_vector_type(8)))  short  bf16x8;
typedef __attribute__((ext_vector_type(4)))  float  f32x4;
typedef __attribute__((ext_vector_type(16))) float  f32x16;

static constexpr int B_=32, C_=32, H_=64, W_=64, K_=1024;

__device__ __forceinline__ unsigned short f2bf(float f){
  unsigned u = __float_as_uint(f);
  u = u + 0x7FFFu + ((u>>16)&1u);        // round-to-nearest-even
  return (unsigned short)(u>>16);
}
__device__ __forceinline__ f32x16 mfma32(bf16x8 a, bf16x8 b, f32x16 c){
  return __builtin_amdgcn_mfma_f32_32x32x16_bf16(a,b,c,0,0,0);
}
__device__ __forceinline__ f32x4 mfma16(bf16x8 a, bf16x8 b, f32x4 c){
  return __builtin_amdgcn_mfma_f32_16x16x32_bf16(a,b,c,0,0,0);
}

// ---------------- prep: f64 codebook, ||e||^2, weight prepack --------------
// wt1p: [p][c2][t4][g4][lane64][e8]   (convT1: K=16 per mfma, ic=c*16+(l>>5)*8+e)
// wt2p: [p][m2][c4][t4][g2][lane64][e8]
// w3p : [t9][c2][lane64][e8]          (conv3 16x16x32: oc=l&15, ic=c*32+(l>>4)*8+e)
__global__ __launch_bounds__(256) void prep_kernel(
    const float* __restrict__ cb, const float* __restrict__ w1,
    const float* __restrict__ w2, const float* __restrict__ w3,
    double* __restrict__ cb64, double* __restrict__ e2,
    unsigned short* __restrict__ wt1p, unsigned short* __restrict__ wt2p,
    unsigned short* __restrict__ w3p, float* __restrict__ zpage) {
  int idx = blockIdx.x*256 + threadIdx.x;
  if (idx < 64) zpage[idx] = 0.f;
  if (idx < K_*C_) cb64[idx] = (double)cb[idx];
  if (idx < K_) {
    double s = 0.0;
    #pragma unroll
    for (int c=0;c<C_;++c){ double v=(double)cb[idx*C_+c]; s+=v*v; }
    e2[idx] = s;
  }
  if (idx < 65536) {  // wt1p
    int e=idx&7, lane=(idx>>3)&63, g=(idx>>9)&3, t=(idx>>11)&3, c=(idx>>13)&1, p=idx>>14;
    int ic = c*16 + (lane>>5)*8 + e;
    int oc = g*32 + (lane&31);
    int ky = 2*(t>>1) + (p>>1), kx = 2*(t&1) + (p&1);
    wt1p[idx] = f2bf(w1[((ic*128+oc)*4+ky)*4+kx]);
  }
  if (idx < 131072) { // wt2p
    int e=idx&7, lane=(idx>>3)&63, g=(idx>>9)&1, t=(idx>>10)&3, c=(idx>>12)&3, m=(idx>>14)&1, p=idx>>15;
    int ic = m*64 + c*16 + (lane>>5)*8 + e;
    int oc = g*32 + (lane&31);
    int ky = 2*(t>>1) + (p>>1), kx = 2*(t&1) + (p&1);
    wt2p[idx] = f2bf(w2[((ic*64+oc)*4+ky)*4+kx]);
  }
  if (idx < 9216) {   // w3p
    int e=idx&7, lane=(idx>>3)&63, c=(idx>>9)&1, t=idx>>10;
    int ic = c*32 + ((lane>>4)&3)*8 + e;
    int oc = lane&15;
    int dy = t/3, dx = t - 3*dy;
    w3p[idx] = (oc<3) ? f2bf(w3[((oc*64+ic)*3+dy)*3+dx]) : (unsigned short)0;
  }
}

// ---------------- quantize (f64 exact argmin) + emit q bf16 ----------------
__global__ __launch_bounds__(256) void quant_kernel(
    const float* __restrict__ z, const float* __restrict__ cb,
    const double* __restrict__ cb64, const double* __restrict__ e2,
    unsigned short* __restrict__ q) {
  int n = blockIdx.x*256 + threadIdx.x;     // 0..131071
  int b = n >> 12, hw = n & 4095;
  const float* zp = z + (((size_t)b*C_) << 12) + hw;
  double zr[C_];
  #pragma unroll
  for (int c=0;c<C_;++c) zr[c] = (double)zp[(size_t)c<<12];
  double best = -1e300; int bi = 0;
  for (int k=0;k<K_;++k) {
    const double* e = cb64 + k*C_;          // wave-uniform -> s_load
    double a0=0,a1=0,a2=0,a3=0;
    #pragma unroll
    for (int c=0;c<C_;c+=4) {
      a0 += zr[c  ]*e[c  ]; a1 += zr[c+1]*e[c+1];
      a2 += zr[c+2]*e[c+2]; a3 += zr[c+3]*e[c+3];
    }
    double s = 2.0*((a0+a1)+(a2+a3)) - e2[k];
    if (s > best) { best = s; bi = k; }
  }
  const float* crow = cb + bi*C_;
  unsigned short tmp[C_];
  #pragma unroll
  for (int c=0;c<C_;++c) tmp[c] = f2bf(crow[c]);
  bf16x8* qp = (bf16x8*)(q + (size_t)n*C_);
  #pragma unroll
  for (int v=0;v<4;++v) qp[v] = ((bf16x8*)tmp)[v];
}

// ---------------- convT1: 32->128, parity implicit GEMM --------------------
// block: 4 waves = 4 parities; per wave: 2 Y-rows x 32 X x 128 OC (4 ocg)
__global__ __launch_bounds__(256) void convt1_kernel(
    const unsigned short* __restrict__ q, const unsigned short* __restrict__ wt1p,
    const float* __restrict__ b1, const float* __restrict__ zpage,
    unsigned short* __restrict__ x1, int b0) {
  __shared__ unsigned short At[4*4*34*8];   // [k8][r][c][8] 8.5KB
  int tid = threadIdx.x;
  int p = tid>>6, py=(tid>>7)&1, px=(tid>>6)&1;
  int lane = tid&63, xi = lane&31, half = lane>>5, ocl = lane&31;
  int bl = blockIdx.z, b = b0 + bl;
  int Y0 = blockIdx.y*2, X0 = blockIdx.x*32;

  for (int s = tid; s < 544; s += 256) {
    int t = (s*1928)>>16;                   // s/34  (exact for s<1632)
    int c = s - t*34;
    int r = t & 3, k8 = t >> 2;
    int hg = Y0-1+r, wg = X0-1+c;
    const unsigned short* src =
        (hg>=0 && hg<64 && wg>=0 && wg<64)
            ? q + (((size_t)b*64 + hg)*64 + wg)*32 + k8*8
            : (const unsigned short*)zpage;
    *(bf16x8*)&At[s*8] = *(const bf16x8*)src;
  }
  __syncthreads();

  f32x16 acc[2][4];
  #pragma unroll
  for (int g=0;g<4;++g){
    float bv = b1[g*32+ocl];
    #pragma unroll
    for (int yr=0;yr<2;++yr){
      #pragma unroll
      for (int r=0;r<16;++r) acc[yr][g][r]=bv;
    }
  }

  #pragma unroll
  for (int c16=0;c16<2;++c16) {
    #pragma unroll
    for (int t=0;t<4;++t) {
      int j=t>>1, kx=t&1;
      int col = xi+px+kx;
      int rb = (c16*2+half)*4 + py + j;
      bf16x8 a0 = *(const bf16x8*)&At[((rb+0)*34+col)*8];
      bf16x8 a1 = *(const bf16x8*)&At[((rb+1)*34+col)*8];
      const unsigned short* wb = wt1p + ((size_t)(((p*2+c16)*4+t)*4)*64 + lane)*8;
      #pragma unroll
      for (int g=0;g<4;++g) {
        bf16x8 bf = *(const bf16x8*)(wb + g*512);
        acc[0][g] = mfma32(a0, bf, acc[0][g]);
        acc[1][g] = mfma32(a1, bf, acc[1][g]);
      }
    }
  }

  #pragma unroll
  for (int yr=0;yr<2;++yr) {
    #pragma unroll
    for (int g=0;g<4;++g) {
      unsigned short* dst = x1 + ((((size_t)bl*4 + p)*64 + (Y0+yr))*64 + X0)*128 + g*32 + ocl;
      #pragma unroll
      for (int r=0;r<16;++r) {
        int xo = (r&3) + 8*(r>>2) + 4*half;
        dst[(size_t)xo*128] = f2bf(fmaxf(acc[yr][g][r], 0.f));
      }
    }
  }
}

// ---------------- convT2: 128->64, parity implicit GEMM --------------------
// block: 4 waves = 4 parities; per wave: 4 Y-rows x 32 X x 64 OC (2 ocg)
__global__ __launch_bounds__(256) void convt2_kernel(
    const unsigned short* __restrict__ x1, const unsigned short* __restrict__ wt2p,
    const float* __restrict__ b2, const float* __restrict__ zpage,
    unsigned short* __restrict__ x2) {
  __shared__ unsigned short At[8*6*34*8];   // 26.1KB
  int tid = threadIdx.x;
  int p = tid>>6, py=(tid>>7)&1, px=(tid>>6)&1;
  int lane = tid&63, xi = lane&31, half = lane>>5, ocl = lane&31;
  int bl = blockIdx.z;
  int Y0 = blockIdx.y*4, X0 = blockIdx.x*32;

  f32x16 acc[4][2];
  #pragma unroll
  for (int g=0;g<2;++g){
    float bv = b2[g*32+ocl];
    #pragma unroll
    for (int yr=0;yr<4;++yr){
      #pragma unroll
      for (int r=0;r<16;++r) acc[yr][g][r]=bv;
    }
  }

  for (int m=0;m<2;++m) {
    __syncthreads();
    for (int s = tid; s < 1632; s += 256) {
      int t = (s*1928)>>16;                 // s/34
      int c = s - t*34;
      int k8 = (t*43)>>8;                   // t/6 (t<48)
      int r = t - k8*6;
      int hg = Y0-1+r, wg = X0-1+c;
      const unsigned short* src =
          (hg>=0 && hg<128 && wg>=0 && wg<128)
              ? x1 + ((((size_t)bl*4 + (hg&1)*2+(wg&1))*64 + (hg>>1))*64 + (wg>>1))*128 + m*64 + k8*8
              : (const unsigned short*)zpage;
      *(bf16x8*)&At[s*8] = *(const bf16x8*)src;
    }
    __syncthreads();

    #pragma unroll
    for (int c16=0;c16<4;++c16) {
      #pragma unroll
      for (int t=0;t<4;++t) {
        int j=t>>1, kx=t&1;
        int col = xi+px+kx;
        int rb = (c16*2+half)*6 + py + j;
        bf16x8 a0 = *(const bf16x8*)&At[((rb+0)*34+col)*8];
        bf16x8 a1 = *(const bf16x8*)&At[((rb+1)*34+col)*8];
        bf16x8 a2 = *(const bf16x8*)&At[((rb+2)*34+col)*8];
        bf16x8 a3 = *(const bf16x8*)&At[((rb+3)*34+col)*8];
        const unsigned short* wb = wt2p + ((size_t)(((((p*2+m)*4+c16)*4+t)*2))*64 + lane)*8;
        bf16x8 bf0 = *(const bf16x8*)wb;
        bf16x8 bf1 = *(const bf16x8*)(wb + 512);
        acc[0][0]=mfma32(a0,bf0,acc[0][0]); acc[1][0]=mfma32(a1,bf0,acc[1][0]);
        acc[2][0]=mfma32(a2,bf0,acc[2][0]); acc[3][0]=mfma32(a3,bf0,acc[3][0]);
        acc[0][1]=mfma32(a0,bf1,acc[0][1]); acc[1][1]=mfma32(a1,bf1,acc[1][1]);
        acc[2][1]=mfma32(a2,bf1,acc[2][1]); acc[3][1]=mfma32(a3,bf1,acc[3][1]);
      }
    }
  }

  #pragma unroll
  for (int yr=0;yr<4;++yr) {
    #pragma unroll
    for (int g=0;g<2;++g) {
      unsigned short* dst = x2 + ((((size_t)bl*4 + p)*128 + (Y0+yr))*128 + X0)*64 + g*32 + ocl;
      #pragma unroll
      for (int r=0;r<16;++r) {
        int xo = (r&3) + 8*(r>>2) + 4*half;
        dst[(size_t)xo*64] = f2bf(fmaxf(acc[yr][g][r], 0.f));
      }
    }
  }
}

// ---------------- conv3 3x3 64->3(+13 pad) + sigmoid, MFMA 16x16x32 --------
// block: 4 waves = 4 consecutive output rows; per wave: 64 X (4 M-tiles)
__global__ __launch_bounds__(256) void conv3_kernel(
    const unsigned short* __restrict__ x2, const unsigned short* __restrict__ w3p,
    const float* __restrict__ b3, const float* __restrict__ zpage,
    float* __restrict__ out, int b0) {
  __shared__ unsigned short Xt[4*6*66*8];   // 25.3KB
  int tid = threadIdx.x, w = tid>>6, lane = tid&63;
  int xi = lane&15, k8A = (lane>>4)&3, oc = lane&15;
  int bl = blockIdx.z, b = b0 + bl;
  int y0 = blockIdx.y*4, x0 = blockIdx.x*64;
  int y = y0 + w;

  f32x4 acc[4];
  float bv = (oc<3) ? b3[oc] : 0.f;
  #pragma unroll
  for (int mt=0;mt<4;++mt){ acc[mt][0]=bv; acc[mt][1]=bv; acc[mt][2]=bv; acc[mt][3]=bv; }

  for (int c=0;c<2;++c) {
    __syncthreads();
    for (int s = tid; s < 1584; s += 256) {
      int t = (s*993)>>16;                  // s/66 (exact for s<1584)
      int cc = s - t*66;
      int k8 = (t*43)>>8;                   // t/6 (t<24)
      int r = t - k8*6;
      int rf = y0-1+r, cf = x0-1+cc;
      const unsigned short* src =
          (rf>=0 && rf<256 && cf>=0 && cf<256)
              ? x2 + ((((size_t)bl*4 + (rf&1)*2+(cf&1))*128 + (rf>>1))*128 + (cf>>1))*64 + c*32 + k8*8
              : (const unsigned short*)zpage;
      *(bf16x8*)&Xt[s*8] = *(const bf16x8*)src;
    }
    __syncthreads();

    #pragma unroll
    for (int t=0;t<9;++t) {
      int dy = t/3, dx = t - 3*dy;
      bf16x8 bf = *(const bf16x8*)(w3p + ((size_t)(t*2+c)*64 + lane)*8);
      #pragma unroll
      for (int mt=0;mt<4;++mt) {
        bf16x8 a = *(const bf16x8*)&Xt[((size_t)(k8A*6 + (w+dy))*66 + (mt*16 + xi + dx))*8];
        acc[mt] = mfma16(a, bf, acc[mt]);
      }
    }
  }

  if (oc < 3) {
    #pragma unroll
    for (int mt=0;mt<4;++mt) {
      f32x4 v;
      #pragma unroll
      for (int r=0;r<4;++r) v[r] = 1.f/(1.f + __expf(-acc[mt][r]));
      int x = x0 + mt*16 + ((lane>>4)&3)*4;
      *(f32x4*)(out + (((size_t)b*3 + oc)*256 + y)*256 + x) = v;
    }
  }
}

// ---------------------------------------------------------------------------
extern "C" void kernel_launch(void* const* d_in, const int* in_sizes, int n_in,
                              void* d_out, int out_size, void* d_ws, size_t ws_size,
                              hipStream_t stream) {
  const float* z  = (const float*)d_in[0];
  const float* cb = (const float*)d_in[1];
  const float* w1 = (const float*)d_in[2];
  const float* b1 = (const float*)d_in[3];
  const float* w2 = (const float*)d_in[4];
  const float* b2 = (const float*)d_in[5];
  const float* w3 = (const float*)d_in[6];
  const float* b3 = (const float*)d_in[7];
  float* out = (float*)d_out;

  char* ws = (char*)d_ws;
  size_t off = 0;
  auto alloc = [&](size_t bytes) -> void* {
    void* p = (void*)(ws + off);
    off += (bytes + 255) & ~(size_t)255;
    return p;
  };
  double* cb64        = (double*)alloc((size_t)K_*C_*8);
  double* e2          = (double*)alloc((size_t)K_*8);
  float*  zpage       = (float*)alloc(256);
  unsigned short* wt1p= (unsigned short*)alloc((size_t)65536*2);
  unsigned short* wt2p= (unsigned short*)alloc((size_t)131072*2);
  unsigned short* w3p = (unsigned short*)alloc((size_t)9216*2);
  unsigned short* q   = (unsigned short*)alloc((size_t)B_*H_*W_*C_*2);
  size_t fixed = off;

  // per-batch: x1 [4][64][64][128] bf16 (4.19MB) + x2 [4][128][128][64] bf16 (8.39MB)
  size_t per_b = ((size_t)4*64*64*128 + (size_t)4*128*128*64) * 2;
  long long avail = (long long)ws_size - (long long)fixed;
  int chunk = (avail >= (long long)per_b) ? (int)(avail / (long long)per_b) : 1;
  if (chunk > B_) chunk = B_;
  unsigned short* x1 = (unsigned short*)alloc((size_t)chunk*4*64*64*128*2);
  unsigned short* x2 = (unsigned short*)alloc((size_t)chunk*4*128*128*64*2);

  prep_kernel<<<512, 256, 0, stream>>>(cb, w1, w2, w3, cb64, e2, wt1p, wt2p, w3p, zpage);
  quant_kernel<<<512, 256, 0, stream>>>(z, cb, cb64, e2, q);

  for (int b0 = 0; b0 < B_; b0 += chunk) {
    int nb = (B_ - b0 < chunk) ? (B_ - b0) : chunk;
    convt1_kernel<<<dim3(2,32,nb), 256, 0, stream>>>(q, wt1p, b1, zpage, x1, b0);
    convt2_kernel<<<dim3(4,32,nb), 256, 0, stream>>>(x1, wt2p, b2, zpage, x2);
    conv3_kernel <<<dim3(4,64,nb), 256, 0, stream>>>(x2, w3p, b3, zpage, out, b0);
  }
}

// Round 4
// 827.257 us; speedup vs baseline: 3.6389x; 1.2426x over previous
//
#include <hip/hip_runtime.h>
#include <hip/hip_bf16.h>

// ---------------------------------------------------------------------------
// VQ-VAE forward, MFMA edition, round 4.
//   quantize: bf16x2-split MFMA screening (16x16x32, K=32 in one mfma) with
//             best/second margin; uncertain positions (gap < 0.02) re-solved
//             exactly in f64 by a wave-per-position refine kernel.
//   convT1 32->128 s2 : MFMA 32x32x16, parity-decomposed implicit GEMM
//   convT2 128->64 s2 : same scheme
//   conv3 3x3 64->3 + sigmoid : MFMA 16x16x32 -> out f32 NCHW
// ---------------------------------------------------------------------------

typedef __attribute__((ext_vector_type(8)))  short  bf16x8;
typedef __attribute__((ext_vector_type(4)))  float  f32x4;
typedef __attribute__((ext_vector_type(16))) float  f32x16;

static constexpr int B_=32, C_=32, H_=64, W_=64, K_=1024;

__device__ __forceinline__ unsigned short f2bf(float f){
  unsigned u = __float_as_uint(f);
  u = u + 0x7FFFu + ((u>>16)&1u);        // round-to-nearest-even
  return (unsigned short)(u>>16);
}
__device__ __forceinline__ float bf2f(unsigned short h){
  return __uint_as_float(((unsigned)h)<<16);
}
__device__ __forceinline__ f32x16 mfma32(bf16x8 a, bf16x8 b, f32x16 c){
  return __builtin_amdgcn_mfma_f32_32x32x16_bf16(a,b,c,0,0,0);
}
__device__ __forceinline__ f32x4 mfma16(bf16x8 a, bf16x8 b, f32x4 c){
  return __builtin_amdgcn_mfma_f32_16x16x32_bf16(a,b,c,0,0,0);
}

// ---------------- prep: f64 codebook, e2, bf16x2 codebook, weight prepack --
// wt1p: [p][c2][t4][g4][lane64][e8]   (convT1: ic=c*16+(l>>5)*8+e)
// wt2p: [p][m2][c4][t4][g2][lane64][e8]
// w3p : [t9][c2][lane64][e8]          (conv3: oc=l&15, ic=c*32+(l>>4)*8+e)
__global__ __launch_bounds__(256) void prep_kernel(
    const float* __restrict__ cb, const float* __restrict__ w1,
    const float* __restrict__ w2, const float* __restrict__ w3,
    double* __restrict__ cb64, double* __restrict__ e2,
    unsigned short* __restrict__ cbp_hi, unsigned short* __restrict__ cbp_lo,
    float* __restrict__ e2h,
    unsigned short* __restrict__ wt1p, unsigned short* __restrict__ wt2p,
    unsigned short* __restrict__ w3p, float* __restrict__ zpage,
    int* __restrict__ cnt) {
  int idx = blockIdx.x*256 + threadIdx.x;
  if (idx == 0) cnt[0] = 0;
  if (idx < 64) zpage[idx] = 0.f;
  if (idx < K_*C_) {
    float v = cb[idx];
    cb64[idx] = (double)v;
    unsigned short h = f2bf(v);
    cbp_hi[idx] = h;
    cbp_lo[idx] = f2bf(v - bf2f(h));
  }
  if (idx < K_) {
    double s = 0.0;
    #pragma unroll
    for (int c=0;c<C_;++c){ double v=(double)cb[idx*C_+c]; s+=v*v; }
    e2[idx] = s;
    e2h[idx] = -0.5f * (float)s;
  }
  if (idx < 65536) {  // wt1p
    int e=idx&7, lane=(idx>>3)&63, g=(idx>>9)&3, t=(idx>>11)&3, c=(idx>>13)&1, p=idx>>14;
    int ic = c*16 + (lane>>5)*8 + e;
    int oc = g*32 + (lane&31);
    int ky = 2*(t>>1) + (p>>1), kx = 2*(t&1) + (p&1);
    wt1p[idx] = f2bf(w1[((ic*128+oc)*4+ky)*4+kx]);
  }
  if (idx < 131072) { // wt2p
    int e=idx&7, lane=(idx>>3)&63, g=(idx>>9)&1, t=(idx>>10)&3, c=(idx>>12)&3, m=(idx>>14)&1, p=idx>>15;
    int ic = m*64 + c*16 + (lane>>5)*8 + e;
    int oc = g*32 + (lane&31);
    int ky = 2*(t>>1) + (p>>1), kx = 2*(t&1) + (p&1);
    wt2p[idx] = f2bf(w2[((ic*64+oc)*4+ky)*4+kx]);
  }
  if (idx < 9216) {   // w3p
    int e=idx&7, lane=(idx>>3)&63, c=(idx>>9)&1, t=idx>>10;
    int ic = c*32 + ((lane>>4)&3)*8 + e;
    int oc = lane&15;
    int dy = t/3, dx = t - 3*dy;
    w3p[idx] = (oc<3) ? f2bf(w3[((oc*64+ic)*3+dy)*3+dx]) : (unsigned short)0;
  }
}

// ---------------- z transpose + bf16x2 split: zt[n][c] --------------------
__global__ __launch_bounds__(256) void zprep_kernel(
    const float* __restrict__ z, unsigned short* __restrict__ zth,
    unsigned short* __restrict__ ztl) {
  int n = blockIdx.x*256 + threadIdx.x;     // 0..131071
  int b = n >> 12, hw = n & 4095;
  const float* zp = z + (((size_t)b*C_) << 12) + hw;
  unsigned short th[C_], tl[C_];
  #pragma unroll
  for (int c=0;c<C_;++c) {
    float v = zp[(size_t)c<<12];
    unsigned short h = f2bf(v);
    th[c] = h;
    tl[c] = f2bf(v - bf2f(h));
  }
  bf16x8* dh = (bf16x8*)(zth + (size_t)n*C_);
  bf16x8* dl = (bf16x8*)(ztl + (size_t)n*C_);
  #pragma unroll
  for (int v=0;v<4;++v){ dh[v]=((bf16x8*)th)[v]; dl[v]=((bf16x8*)tl)[v]; }
}

// ---------------- MFMA argmin screening ------------------------------------
// wave: 32 positions (2 M-tiles of 16); block: 4 waves = 128 positions.
// N-loop over 1024 codes in 4 LDS chunks of 256. acc = z.e - 0.5||e||^2.
__global__ __launch_bounds__(256) void quantm_kernel(
    const unsigned short* __restrict__ zth, const unsigned short* __restrict__ ztl,
    const unsigned short* __restrict__ cbp_hi, const unsigned short* __restrict__ cbp_lo,
    const float* __restrict__ e2h, const float* __restrict__ cb,
    unsigned short* __restrict__ q, int* __restrict__ cnt, int* __restrict__ list) {
  __shared__ bf16x8 ch[1024], cl[1024];     // 16KB + 16KB
  __shared__ float  el[256];
  int tid = threadIdx.x, lane = tid&63, wv = tid>>6;
  int m0 = blockIdx.x*128 + wv*32;
  int colL = lane&15, g = lane>>4;

  bf16x8 ah[2], al[2];
  #pragma unroll
  for (int mt=0;mt<2;++mt) {
    int pos = m0 + mt*16 + colL;
    ah[mt] = *(const bf16x8*)(zth + (size_t)pos*C_ + g*8);
    al[mt] = *(const bf16x8*)(ztl + (size_t)pos*C_ + g*8);
  }

  float b1[2][4], b2[2][4]; int i1[2][4];
  #pragma unroll
  for (int mt=0;mt<2;++mt)
    #pragma unroll
    for (int r=0;r<4;++r){ b1[mt][r]=-3e38f; b2[mt][r]=-3e38f; i1[mt][r]=0; }

  for (int cb0 = 0; cb0 < K_; cb0 += 256) {
    __syncthreads();
    {
      const bf16x8* sh = (const bf16x8*)cbp_hi + cb0*4;
      const bf16x8* sl = (const bf16x8*)cbp_lo + cb0*4;
      #pragma unroll
      for (int v=0;v<4;++v){ ch[tid + v*256] = sh[tid + v*256];
                             cl[tid + v*256] = sl[tid + v*256]; }
      el[tid] = e2h[cb0 + tid];
    }
    __syncthreads();
    #pragma unroll
    for (int nt=0; nt<16; ++nt) {
      int cloc = nt*16 + colL;
      float ei = el[cloc];
      bf16x8 bh = ch[cloc*4 + g];
      bf16x8 bl = cl[cloc*4 + g];
      int nidx = cb0 + cloc;
      #pragma unroll
      for (int mt=0;mt<2;++mt) {
        f32x4 acc = {ei, ei, ei, ei};
        acc = mfma16(al[mt], bh, acc);
        acc = mfma16(ah[mt], bl, acc);
        acc = mfma16(ah[mt], bh, acc);
        #pragma unroll
        for (int r=0;r<4;++r) {
          float s = acc[r];
          b2[mt][r] = fmaxf(b2[mt][r], fminf(s, b1[mt][r]));
          if (s > b1[mt][r]) { b1[mt][r] = s; i1[mt][r] = nidx; }
        }
      }
    }
  }

  // merge across the 16 lanes of each C-row group
  #pragma unroll
  for (int mask=1; mask<16; mask<<=1) {
    #pragma unroll
    for (int mt=0;mt<2;++mt)
      #pragma unroll
      for (int r=0;r<4;++r) {
        float o1 = __shfl_xor(b1[mt][r], mask);
        float o2 = __shfl_xor(b2[mt][r], mask);
        int   oi = __shfl_xor(i1[mt][r], mask);
        float nb2 = fmaxf(fminf(b1[mt][r], o1), fmaxf(b2[mt][r], o2));
        if (o1 > b1[mt][r]) { b1[mt][r] = o1; i1[mt][r] = oi; }
        b2[mt][r] = nb2;
      }
  }

  // write q rows (16 lanes x 2 channels) + refine list on small margin
  #pragma unroll
  for (int mt=0;mt<2;++mt)
    #pragma unroll
    for (int r=0;r<4;++r) {
      int m = m0 + mt*16 + g*4 + r;
      int idx = i1[mt][r];
      unsigned h0 = f2bf(cb[idx*C_ + 2*colL]);
      unsigned h1 = f2bf(cb[idx*C_ + 2*colL + 1]);
      ((unsigned*)q)[(size_t)m*16 + colL] = h0 | (h1<<16);
      if (colL == 0 && (b1[mt][r] - b2[mt][r]) < 0.02f) {
        int slot = atomicAdd(cnt, 1);
        list[slot] = m;
      }
    }
}

// ---------------- exact f64 refine, one wave per position ------------------
__global__ __launch_bounds__(256) void refine_kernel(
    const int* __restrict__ cnt, const int* __restrict__ list,
    const float* __restrict__ z, const double* __restrict__ cb64,
    const double* __restrict__ e2, const float* __restrict__ cb,
    unsigned short* __restrict__ q) {
  int lane = threadIdx.x & 63;
  int wv = (blockIdx.x*256 + threadIdx.x) >> 6;
  int n_ref = cnt[0];
  for (int w = wv; w < n_ref; w += 1024) {
    int m = list[w];
    int b = m >> 12, hw = m & 4095;
    const float* zp = z + (((size_t)b*C_) << 12) + hw;
    double zr[C_];
    #pragma unroll
    for (int c=0;c<C_;++c) zr[c] = (double)zp[(size_t)c<<12];
    double best = -1e300; int bi = 0;
    for (int kk=0; kk<16; ++kk) {
      int k = kk*64 + lane;
      const double* e = cb64 + k*C_;
      double a0=0,a1=0,a2=0,a3=0;
      #pragma unroll
      for (int c=0;c<C_;c+=4) {
        a0 += zr[c  ]*e[c  ]; a1 += zr[c+1]*e[c+1];
        a2 += zr[c+2]*e[c+2]; a3 += zr[c+3]*e[c+3];
      }
      double s = 2.0*((a0+a1)+(a2+a3)) - e2[k];
      if (s > best) { best = s; bi = k; }
    }
    #pragma unroll
    for (int mask=1; mask<64; mask<<=1) {
      double ob = __shfl_xor(best, mask);
      int    oi = __shfl_xor(bi, mask);
      if (ob > best || (ob == best && oi < bi)) { best = ob; bi = oi; }
    }
    if (lane < 16) {
      unsigned h0 = f2bf(cb[bi*C_ + 2*lane]);
      unsigned h1 = f2bf(cb[bi*C_ + 2*lane + 1]);
      ((unsigned*)q)[(size_t)m*16 + lane] = h0 | (h1<<16);
    }
  }
}

// ---------------- convT1: 32->128, parity implicit GEMM --------------------
__global__ __launch_bounds__(256) void convt1_kernel(
    const unsigned short* __restrict__ q, const unsigned short* __restrict__ wt1p,
    const float* __restrict__ b1, const float* __restrict__ zpage,
    unsigned short* __restrict__ x1, int b0) {
  __shared__ unsigned short At[4*4*34*8];   // [k8][r][c][8] 8.5KB
  int tid = threadIdx.x;
  int p = tid>>6, py=(tid>>7)&1, px=(tid>>6)&1;
  int lane = tid&63, xi = lane&31, half = lane>>5, ocl = lane&31;
  int bl = blockIdx.z, b = b0 + bl;
  int Y0 = blockIdx.y*2, X0 = blockIdx.x*32;

  for (int s = tid; s < 544; s += 256) {
    int t = (s*1928)>>16;                   // s/34
    int c = s - t*34;
    int r = t & 3, k8 = t >> 2;
    int hg = Y0-1+r, wg = X0-1+c;
    const unsigned short* src =
        (hg>=0 && hg<64 && wg>=0 && wg<64)
            ? q + (((size_t)b*64 + hg)*64 + wg)*32 + k8*8
            : (const unsigned short*)zpage;
    *(bf16x8*)&At[s*8] = *(const bf16x8*)src;
  }
  __syncthreads();

  f32x16 acc[2][4];
  #pragma unroll
  for (int g=0;g<4;++g){
    float bv = b1[g*32+ocl];
    #pragma unroll
    for (int yr=0;yr<2;++yr){
      #pragma unroll
      for (int r=0;r<16;++r) acc[yr][g][r]=bv;
    }
  }

  #pragma unroll
  for (int c16=0;c16<2;++c16) {
    #pragma unroll
    for (int t=0;t<4;++t) {
      int j=t>>1, kx=t&1;
      int col = xi+px+kx;
      int rb = (c16*2+half)*4 + py + j;
      bf16x8 a0 = *(const bf16x8*)&At[((rb+0)*34+col)*8];
      bf16x8 a1 = *(const bf16x8*)&At[((rb+1)*34+col)*8];
      const unsigned short* wb = wt1p + ((size_t)(((p*2+c16)*4+t)*4)*64 + lane)*8;
      #pragma unroll
      for (int g=0;g<4;++g) {
        bf16x8 bf = *(const bf16x8*)(wb + g*512);
        acc[0][g] = mfma32(a0, bf, acc[0][g]);
        acc[1][g] = mfma32(a1, bf, acc[1][g]);
      }
    }
  }

  #pragma unroll
  for (int yr=0;yr<2;++yr) {
    #pragma unroll
    for (int g=0;g<4;++g) {
      unsigned short* dst = x1 + ((((size_t)bl*4 + p)*64 + (Y0+yr))*64 + X0)*128 + g*32 + ocl;
      #pragma unroll
      for (int r=0;r<16;++r) {
        int xo = (r&3) + 8*(r>>2) + 4*half;
        dst[(size_t)xo*128] = f2bf(fmaxf(acc[yr][g][r], 0.f));
      }
    }
  }
}

// ---------------- convT2: 128->64, parity implicit GEMM --------------------
__global__ __launch_bounds__(256) void convt2_kernel(
    const unsigned short* __restrict__ x1, const unsigned short* __restrict__ wt2p,
    const float* __restrict__ b2, const float* __restrict__ zpage,
    unsigned short* __restrict__ x2) {
  __shared__ unsigned short At[8*6*34*8];   // 26.1KB
  int tid = threadIdx.x;
  int p = tid>>6, py=(tid>>7)&1, px=(tid>>6)&1;
  int lane = tid&63, xi = lane&31, half = lane>>5, ocl = lane&31;
  int bl = blockIdx.z;
  int Y0 = blockIdx.y*4, X0 = blockIdx.x*32;

  f32x16 acc[4][2];
  #pragma unroll
  for (int g=0;g<2;++g){
    float bv = b2[g*32+ocl];
    #pragma unroll
    for (int yr=0;yr<4;++yr){
      #pragma unroll
      for (int r=0;r<16;++r) acc[yr][g][r]=bv;
    }
  }

  for (int m=0;m<2;++m) {
    __syncthreads();
    for (int s = tid; s < 1632; s += 256) {
      int t = (s*1928)>>16;                 // s/34
      int c = s - t*34;
      int k8 = (t*43)>>8;                   // t/6
      int r = t - k8*6;
      int hg = Y0-1+r, wg = X0-1+c;
      const unsigned short* src =
          (hg>=0 && hg<128 && wg>=0 && wg<128)
              ? x1 + ((((size_t)bl*4 + (hg&1)*2+(wg&1))*64 + (hg>>1))*64 + (wg>>1))*128 + m*64 + k8*8
              : (const unsigned short*)zpage;
      *(bf16x8*)&At[s*8] = *(const bf16x8*)src;
    }
    __syncthreads();

    #pragma unroll
    for (int c16=0;c16<4;++c16) {
      #pragma unroll
      for (int t=0;t<4;++t) {
        int j=t>>1, kx=t&1;
        int col = xi+px+kx;
        int rb = (c16*2+half)*6 + py + j;
        bf16x8 a0 = *(const bf16x8*)&At[((rb+0)*34+col)*8];
        bf16x8 a1 = *(const bf16x8*)&At[((rb+1)*34+col)*8];
        bf16x8 a2 = *(const bf16x8*)&At[((rb+2)*34+col)*8];
        bf16x8 a3 = *(const bf16x8*)&At[((rb+3)*34+col)*8];
        const unsigned short* wb = wt2p + ((size_t)(((((p*2+m)*4+c16)*4+t)*2))*64 + lane)*8;
        bf16x8 bf0 = *(const bf16x8*)wb;
        bf16x8 bf1 = *(const bf16x8*)(wb + 512);
        acc[0][0]=mfma32(a0,bf0,acc[0][0]); acc[1][0]=mfma32(a1,bf0,acc[1][0]);
        acc[2][0]=mfma32(a2,bf0,acc[2][0]); acc[3][0]=mfma32(a3,bf0,acc[3][0]);
        acc[0][1]=mfma32(a0,bf1,acc[0][1]); acc[1][1]=mfma32(a1,bf1,acc[1][1]);
        acc[2][1]=mfma32(a2,bf1,acc[2][1]); acc[3][1]=mfma32(a3,bf1,acc[3][1]);
      }
    }
  }

  #pragma unroll
  for (int yr=0;yr<4;++yr) {
    #pragma unroll
    for (int g=0;g<2;++g) {
      unsigned short* dst = x2 + ((((size_t)bl*4 + p)*128 + (Y0+yr))*128 + X0)*64 + g*32 + ocl;
      #pragma unroll
      for (int r=0;r<16;++r) {
        int xo = (r&3) + 8*(r>>2) + 4*half;
        dst[(size_t)xo*64] = f2bf(fmaxf(acc[yr][g][r], 0.f));
      }
    }
  }
}

// ---------------- conv3 3x3 64->3(+13 pad) + sigmoid, MFMA 16x16x32 --------
__global__ __launch_bounds__(256) void conv3_kernel(
    const unsigned short* __restrict__ x2, const unsigned short* __restrict__ w3p,
    const float* __restrict__ b3, const float* __restrict__ zpage,
    float* __restrict__ out, int b0) {
  __shared__ unsigned short Xt[4*6*66*8];   // 25.3KB
  int tid = threadIdx.x, w = tid>>6, lane = tid&63;
  int xi = lane&15, k8A = (lane>>4)&3, oc = lane&15;
  int bl = blockIdx.z, b = b0 + bl;
  int y0 = blockIdx.y*4, x0 = blockIdx.x*64;
  int y = y0 + w;

  f32x4 acc[4];
  float bv = (oc<3) ? b3[oc] : 0.f;
  #pragma unroll
  for (int mt=0;mt<4;++mt){ acc[mt][0]=bv; acc[mt][1]=bv; acc[mt][2]=bv; acc[mt][3]=bv; }

  for (int c=0;c<2;++c) {
    __syncthreads();
    for (int s = tid; s < 1584; s += 256) {
      int t = (s*993)>>16;                  // s/66
      int cc = s - t*66;
      int k8 = (t*43)>>8;                   // t/6
      int r = t - k8*6;
      int rf = y0-1+r, cf = x0-1+cc;
      const unsigned short* src =
          (rf>=0 && rf<256 && cf>=0 && cf<256)
              ? x2 + ((((size_t)bl*4 + (rf&1)*2+(cf&1))*128 + (rf>>1))*128 + (cf>>1))*64 + c*32 + k8*8
              : (const unsigned short*)zpage;
      *(bf16x8*)&Xt[s*8] = *(const bf16x8*)src;
    }
    __syncthreads();

    #pragma unroll
    for (int t=0;t<9;++t) {
      int dy = t/3, dx = t - 3*dy;
      bf16x8 bf = *(const bf16x8*)(w3p + ((size_t)(t*2+c)*64 + lane)*8);
      #pragma unroll
      for (int mt=0;mt<4;++mt) {
        bf16x8 a = *(const bf16x8*)&Xt[((size_t)(k8A*6 + (w+dy))*66 + (mt*16 + xi + dx))*8];
        acc[mt] = mfma16(a, bf, acc[mt]);
      }
    }
  }

  if (oc < 3) {
    #pragma unroll
    for (int mt=0;mt<4;++mt) {
      f32x4 v;
      #pragma unroll
      for (int r=0;r<4;++r) v[r] = 1.f/(1.f + __expf(-acc[mt][r]));
      int x = x0 + mt*16 + ((lane>>4)&3)*4;
      *(f32x4*)(out + (((size_t)b*3 + oc)*256 + y)*256 + x) = v;
    }
  }
}

// ---------------------------------------------------------------------------
extern "C" void kernel_launch(void* const* d_in, const int* in_sizes, int n_in,
                              void* d_out, int out_size, void* d_ws, size_t ws_size,
                              hipStream_t stream) {
  const float* z  = (const float*)d_in[0];
  const float* cb = (const float*)d_in[1];
  const float* w1 = (const float*)d_in[2];
  const float* b1 = (const float*)d_in[3];
  const float* w2 = (const float*)d_in[4];
  const float* b2 = (const float*)d_in[5];
  const float* w3 = (const float*)d_in[6];
  const float* b3 = (const float*)d_in[7];
  float* out = (float*)d_out;

  char* ws = (char*)d_ws;
  size_t off = 0;
  auto alloc = [&](size_t bytes) -> void* {
    void* p = (void*)(ws + off);
    off += (bytes + 255) & ~(size_t)255;
    return p;
  };
  double* cb64         = (double*)alloc((size_t)K_*C_*8);
  double* e2           = (double*)alloc((size_t)K_*8);
  float*  zpage        = (float*)alloc(256);
  unsigned short* cbph = (unsigned short*)alloc((size_t)K_*C_*2);
  unsigned short* cbpl = (unsigned short*)alloc((size_t)K_*C_*2);
  float*  e2h          = (float*)alloc((size_t)K_*4);
  int*    cnt          = (int*)alloc(256);
  int*    list         = (int*)alloc((size_t)131072*4);
  unsigned short* zth  = (unsigned short*)alloc((size_t)131072*C_*2);
  unsigned short* ztl  = (unsigned short*)alloc((size_t)131072*C_*2);
  unsigned short* wt1p = (unsigned short*)alloc((size_t)65536*2);
  unsigned short* wt2p = (unsigned short*)alloc((size_t)131072*2);
  unsigned short* w3p  = (unsigned short*)alloc((size_t)9216*2);
  unsigned short* q    = (unsigned short*)alloc((size_t)B_*H_*W_*C_*2);
  size_t fixed = off;

  // per-batch: x1 [4][64][64][128] bf16 + x2 [4][128][128][64] bf16
  size_t per_b = ((size_t)4*64*64*128 + (size_t)4*128*128*64) * 2;
  long long avail = (long long)ws_size - (long long)fixed;
  int chunk = (avail >= (long long)per_b) ? (int)(avail / (long long)per_b) : 1;
  if (chunk > B_) chunk = B_;
  unsigned short* x1 = (unsigned short*)alloc((size_t)chunk*4*64*64*128*2);
  unsigned short* x2 = (unsigned short*)alloc((size_t)chunk*4*128*128*64*2);

  prep_kernel<<<512, 256, 0, stream>>>(cb, w1, w2, w3, cb64, e2, cbph, cbpl,
                                       e2h, wt1p, wt2p, w3p, zpage, cnt);
  zprep_kernel<<<512, 256, 0, stream>>>(z, zth, ztl);
  quantm_kernel<<<1024, 256, 0, stream>>>(zth, ztl, cbph, cbpl, e2h, cb,
                                          q, cnt, list);
  refine_kernel<<<256, 256, 0, stream>>>(cnt, list, z, cb64, e2, cb, q);

  for (int b0 = 0; b0 < B_; b0 += chunk) {
    int nb = (B_ - b0 < chunk) ? (B_ - b0) : chunk;
    convt1_kernel<<<dim3(2,32,nb), 256, 0, stream>>>(q, wt1p, b1, zpage, x1, b0);
    convt2_kernel<<<dim3(4,32,nb), 256, 0, stream>>>(x1, wt2p, b2, zpage, x2);
    conv3_kernel <<<dim3(4,64,nb), 256, 0, stream>>>(x2, w3p, b3, zpage, out, b0);
  }
}

// Round 5
// 697.200 us; speedup vs baseline: 4.3177x; 1.1865x over previous
//
#include <hip/hip_runtime.h>
#include <hip/hip_bf16.h>

// ---------------------------------------------------------------------------
// VQ-VAE forward, MFMA edition, round 5.
//   quantize: bf16x2-split MFMA screening + f64 refine (unchanged from r4)
//   Intermediates now channel-grouped full-res planes for coalesced staging:
//     q  [cg4][n=B*64*64][8]      bf16
//     x1 [bl][cg16][128][128][8]  bf16
//     x2 [bl][cg8][256][256][8]   bf16
//   Staging loops read contiguous 16 B/lane (1 KB/wave). Producers write
//   16-B segments per 8-lane group; L2 merges lines (parity-sibling waves).
// ---------------------------------------------------------------------------

typedef __attribute__((ext_vector_type(8)))  short  bf16x8;
typedef __attribute__((ext_vector_type(4)))  float  f32x4;
typedef __attribute__((ext_vector_type(16))) float  f32x16;

static constexpr int B_=32, C_=32, H_=64, W_=64, K_=1024;
static constexpr int NPOS = B_*H_*W_;      // 131072

__device__ __forceinline__ unsigned short f2bf(float f){
  unsigned u = __float_as_uint(f);
  u = u + 0x7FFFu + ((u>>16)&1u);        // round-to-nearest-even
  return (unsigned short)(u>>16);
}
__device__ __forceinline__ float bf2f(unsigned short h){
  return __uint_as_float(((unsigned)h)<<16);
}
__device__ __forceinline__ f32x16 mfma32(bf16x8 a, bf16x8 b, f32x16 c){
  return __builtin_amdgcn_mfma_f32_32x32x16_bf16(a,b,c,0,0,0);
}
__device__ __forceinline__ f32x4 mfma16(bf16x8 a, bf16x8 b, f32x4 c){
  return __builtin_amdgcn_mfma_f32_16x16x32_bf16(a,b,c,0,0,0);
}

// ---------------- prep: f64 codebook, e2, bf16x2 codebook, weight prepack --
__global__ __launch_bounds__(256) void prep_kernel(
    const float* __restrict__ cb, const float* __restrict__ w1,
    const float* __restrict__ w2, const float* __restrict__ w3,
    double* __restrict__ cb64, double* __restrict__ e2,
    unsigned short* __restrict__ cbp_hi, unsigned short* __restrict__ cbp_lo,
    float* __restrict__ e2h,
    unsigned short* __restrict__ wt1p, unsigned short* __restrict__ wt2p,
    unsigned short* __restrict__ w3p, float* __restrict__ zpage,
    int* __restrict__ cnt) {
  int idx = blockIdx.x*256 + threadIdx.x;
  if (idx == 0) cnt[0] = 0;
  if (idx < 64) zpage[idx] = 0.f;
  if (idx < K_*C_) {
    float v = cb[idx];
    cb64[idx] = (double)v;
    unsigned short h = f2bf(v);
    cbp_hi[idx] = h;
    cbp_lo[idx] = f2bf(v - bf2f(h));
  }
  if (idx < K_) {
    double s = 0.0;
    #pragma unroll
    for (int c=0;c<C_;++c){ double v=(double)cb[idx*C_+c]; s+=v*v; }
    e2[idx] = s;
    e2h[idx] = -0.5f * (float)s;
  }
  if (idx < 65536) {  // wt1p  [p][c2][t4][g4][lane64][e8]
    int e=idx&7, lane=(idx>>3)&63, g=(idx>>9)&3, t=(idx>>11)&3, c=(idx>>13)&1, p=idx>>14;
    int ic = c*16 + (lane>>5)*8 + e;
    int oc = g*32 + (lane&31);
    int ky = 2*(t>>1) + (p>>1), kx = 2*(t&1) + (p&1);
    wt1p[idx] = f2bf(w1[((ic*128+oc)*4+ky)*4+kx]);
  }
  if (idx < 131072) { // wt2p  [p][m2][c4][t4][g2][lane64][e8]
    int e=idx&7, lane=(idx>>3)&63, g=(idx>>9)&1, t=(idx>>10)&3, c=(idx>>12)&3, m=(idx>>14)&1, p=idx>>15;
    int ic = m*64 + c*16 + (lane>>5)*8 + e;
    int oc = g*32 + (lane&31);
    int ky = 2*(t>>1) + (p>>1), kx = 2*(t&1) + (p&1);
    wt2p[idx] = f2bf(w2[((ic*64+oc)*4+ky)*4+kx]);
  }
  if (idx < 9216) {   // w3p  [t9][c2][lane64][e8]
    int e=idx&7, lane=(idx>>3)&63, c=(idx>>9)&1, t=idx>>10;
    int ic = c*32 + ((lane>>4)&3)*8 + e;
    int oc = lane&15;
    int dy = t/3, dx = t - 3*dy;
    w3p[idx] = (oc<3) ? f2bf(w3[((oc*64+ic)*3+dy)*3+dx]) : (unsigned short)0;
  }
}

// ---------------- z transpose + bf16x2 split: zt[n][c] --------------------
__global__ __launch_bounds__(256) void zprep_kernel(
    const float* __restrict__ z, unsigned short* __restrict__ zth,
    unsigned short* __restrict__ ztl) {
  int n = blockIdx.x*256 + threadIdx.x;     // 0..131071
  int b = n >> 12, hw = n & 4095;
  const float* zp = z + (((size_t)b*C_) << 12) + hw;
  unsigned short th[C_], tl[C_];
  #pragma unroll
  for (int c=0;c<C_;++c) {
    float v = zp[(size_t)c<<12];
    unsigned short h = f2bf(v);
    th[c] = h;
    tl[c] = f2bf(v - bf2f(h));
  }
  bf16x8* dh = (bf16x8*)(zth + (size_t)n*C_);
  bf16x8* dl = (bf16x8*)(ztl + (size_t)n*C_);
  #pragma unroll
  for (int v=0;v<4;++v){ dh[v]=((bf16x8*)th)[v]; dl[v]=((bf16x8*)tl)[v]; }
}

// ---------------- MFMA argmin screening ------------------------------------
// q layout: [cg4][n][8] bf16 == unsigned view [(cg2? no) ...]:
//   channel pair (2c,2c+1) of position m -> ((unsigned*)q)[((cp>>2)*NPOS + m)*4 + (cp&3)]
__global__ __launch_bounds__(256) void quantm_kernel(
    const unsigned short* __restrict__ zth, const unsigned short* __restrict__ ztl,
    const unsigned short* __restrict__ cbp_hi, const unsigned short* __restrict__ cbp_lo,
    const float* __restrict__ e2h, const float* __restrict__ cb,
    unsigned short* __restrict__ q, int* __restrict__ cnt, int* __restrict__ list) {
  __shared__ bf16x8 ch[1024], cl[1024];     // 16KB + 16KB
  __shared__ float  el[256];
  int tid = threadIdx.x, lane = tid&63, wv = tid>>6;
  int m0 = blockIdx.x*128 + wv*32;
  int colL = lane&15, g = lane>>4;

  bf16x8 ah[2], al[2];
  #pragma unroll
  for (int mt=0;mt<2;++mt) {
    int pos = m0 + mt*16 + colL;
    ah[mt] = *(const bf16x8*)(zth + (size_t)pos*C_ + g*8);
    al[mt] = *(const bf16x8*)(ztl + (size_t)pos*C_ + g*8);
  }

  float b1[2][4], b2[2][4]; int i1[2][4];
  #pragma unroll
  for (int mt=0;mt<2;++mt)
    #pragma unroll
    for (int r=0;r<4;++r){ b1[mt][r]=-3e38f; b2[mt][r]=-3e38f; i1[mt][r]=0; }

  for (int cb0 = 0; cb0 < K_; cb0 += 256) {
    __syncthreads();
    {
      const bf16x8* sh = (const bf16x8*)cbp_hi + cb0*4;
      const bf16x8* sl = (const bf16x8*)cbp_lo + cb0*4;
      #pragma unroll
      for (int v=0;v<4;++v){ ch[tid + v*256] = sh[tid + v*256];
                             cl[tid + v*256] = sl[tid + v*256]; }
      el[tid] = e2h[cb0 + tid];
    }
    __syncthreads();
    #pragma unroll
    for (int nt=0; nt<16; ++nt) {
      int cloc = nt*16 + colL;
      float ei = el[cloc];
      bf16x8 bh = ch[cloc*4 + g];
      bf16x8 bl = cl[cloc*4 + g];
      int nidx = cb0 + cloc;
      #pragma unroll
      for (int mt=0;mt<2;++mt) {
        f32x4 acc = {ei, ei, ei, ei};
        acc = mfma16(al[mt], bh, acc);
        acc = mfma16(ah[mt], bl, acc);
        acc = mfma16(ah[mt], bh, acc);
        #pragma unroll
        for (int r=0;r<4;++r) {
          float s = acc[r];
          b2[mt][r] = fmaxf(b2[mt][r], fminf(s, b1[mt][r]));
          if (s > b1[mt][r]) { b1[mt][r] = s; i1[mt][r] = nidx; }
        }
      }
    }
  }

  #pragma unroll
  for (int mask=1; mask<16; mask<<=1) {
    #pragma unroll
    for (int mt=0;mt<2;++mt)
      #pragma unroll
      for (int r=0;r<4;++r) {
        float o1 = __shfl_xor(b1[mt][r], mask);
        float o2 = __shfl_xor(b2[mt][r], mask);
        int   oi = __shfl_xor(i1[mt][r], mask);
        float nb2 = fmaxf(fminf(b1[mt][r], o1), fmaxf(b2[mt][r], o2));
        if (o1 > b1[mt][r]) { b1[mt][r] = o1; i1[mt][r] = oi; }
        b2[mt][r] = nb2;
      }
  }

  #pragma unroll
  for (int mt=0;mt<2;++mt)
    #pragma unroll
    for (int r=0;r<4;++r) {
      int m = m0 + mt*16 + g*4 + r;
      int idx = i1[mt][r];
      unsigned h0 = f2bf(cb[idx*C_ + 2*colL]);
      unsigned h1 = f2bf(cb[idx*C_ + 2*colL + 1]);
      ((unsigned*)q)[(((size_t)(colL>>2))*NPOS + m)*4 + (colL&3)] = h0 | (h1<<16);
      if (colL == 0 && (b1[mt][r] - b2[mt][r]) < 0.02f) {
        int slot = atomicAdd(cnt, 1);
        list[slot] = m;
      }
    }
}

// ---------------- exact f64 refine, one wave per position ------------------
__global__ __launch_bounds__(256) void refine_kernel(
    const int* __restrict__ cnt, const int* __restrict__ list,
    const float* __restrict__ z, const double* __restrict__ cb64,
    const double* __restrict__ e2, const float* __restrict__ cb,
    unsigned short* __restrict__ q) {
  int lane = threadIdx.x & 63;
  int wv = (blockIdx.x*256 + threadIdx.x) >> 6;
  int n_ref = cnt[0];
  for (int w = wv; w < n_ref; w += 1024) {
    int m = list[w];
    int b = m >> 12, hw = m & 4095;
    const float* zp = z + (((size_t)b*C_) << 12) + hw;
    double zr[C_];
    #pragma unroll
    for (int c=0;c<C_;++c) zr[c] = (double)zp[(size_t)c<<12];
    double best = -1e300; int bi = 0;
    for (int kk=0; kk<16; ++kk) {
      int k = kk*64 + lane;
      const double* e = cb64 + k*C_;
      double a0=0,a1=0,a2=0,a3=0;
      #pragma unroll
      for (int c=0;c<C_;c+=4) {
        a0 += zr[c  ]*e[c  ]; a1 += zr[c+1]*e[c+1];
        a2 += zr[c+2]*e[c+2]; a3 += zr[c+3]*e[c+3];
      }
      double s = 2.0*((a0+a1)+(a2+a3)) - e2[k];
      if (s > best) { best = s; bi = k; }
    }
    #pragma unroll
    for (int mask=1; mask<64; mask<<=1) {
      double ob = __shfl_xor(best, mask);
      int    oi = __shfl_xor(bi, mask);
      if (ob > best || (ob == best && oi < bi)) { best = ob; bi = oi; }
    }
    if (lane < 16) {
      unsigned h0 = f2bf(cb[bi*C_ + 2*lane]);
      unsigned h1 = f2bf(cb[bi*C_ + 2*lane + 1]);
      ((unsigned*)q)[(((size_t)(lane>>2))*NPOS + m)*4 + (lane&3)] = h0 | (h1<<16);
    }
  }
}

// ---------------- convT1: 32->128, parity implicit GEMM --------------------
// in: q [cg4][n][8]; out: x1 [bl][cg16][128][128][8]
__global__ __launch_bounds__(256) void convt1_kernel(
    const unsigned short* __restrict__ q, const unsigned short* __restrict__ wt1p,
    const float* __restrict__ b1, const float* __restrict__ zpage,
    unsigned short* __restrict__ x1, int b0) {
  __shared__ unsigned short At[4*4*34*8];   // [k8][r][c][8] 8.5KB
  int tid = threadIdx.x;
  int p = tid>>6, py=(tid>>7)&1, px=(tid>>6)&1;
  int lane = tid&63, xi = lane&31, half = lane>>5, ocl = lane&31;
  int bl = blockIdx.z, b = b0 + bl;
  int Y0 = blockIdx.y*2, X0 = blockIdx.x*32;

  for (int s = tid; s < 544; s += 256) {
    int t = (s*1928)>>16;                   // s/34
    int c = s - t*34;
    int r = t & 3, k8 = t >> 2;
    int hg = Y0-1+r, wg = X0-1+c;
    const unsigned short* src =
        (hg>=0 && hg<64 && wg>=0 && wg<64)
            ? q + ((size_t)k8*NPOS + ((b<<12) + hg*64 + wg))*8
            : (const unsigned short*)zpage;
    *(bf16x8*)&At[s*8] = *(const bf16x8*)src;
  }
  __syncthreads();

  f32x16 acc[2][4];
  #pragma unroll
  for (int g=0;g<4;++g){
    float bv = b1[g*32+ocl];
    #pragma unroll
    for (int yr=0;yr<2;++yr){
      #pragma unroll
      for (int r=0;r<16;++r) acc[yr][g][r]=bv;
    }
  }

  #pragma unroll
  for (int c16=0;c16<2;++c16) {
    #pragma unroll
    for (int t=0;t<4;++t) {
      int j=t>>1, kx=t&1;
      int col = xi+px+kx;
      int rb = (c16*2+half)*4 + py + j;
      bf16x8 a0 = *(const bf16x8*)&At[((rb+0)*34+col)*8];
      bf16x8 a1 = *(const bf16x8*)&At[((rb+1)*34+col)*8];
      const unsigned short* wb = wt1p + ((size_t)(((p*2+c16)*4+t)*4)*64 + lane)*8;
      #pragma unroll
      for (int g=0;g<4;++g) {
        bf16x8 bf = *(const bf16x8*)(wb + g*512);
        acc[0][g] = mfma32(a0, bf, acc[0][g]);
        acc[1][g] = mfma32(a1, bf, acc[1][g]);
      }
    }
  }

  #pragma unroll
  for (int yr=0;yr<2;++yr) {
    int Y = 2*(Y0+yr)+py;
    #pragma unroll
    for (int g=0;g<4;++g) {
      int oc = g*32 + ocl, cg = oc>>3, o8 = oc&7;
      unsigned short* dst = x1 + ((((size_t)bl*16 + cg)*128 + Y)*128 + (2*X0+px))*8 + o8;
      #pragma unroll
      for (int r=0;r<16;++r) {
        int xo = (r&3) + 8*(r>>2) + 4*half;
        dst[(size_t)xo*16] = f2bf(fmaxf(acc[yr][g][r], 0.f));
      }
    }
  }
}

// ---------------- convT2: 128->64, parity implicit GEMM --------------------
// in: x1 [bl][cg16][128][128][8]; out: x2 [bl][cg8][256][256][8]
__global__ __launch_bounds__(256) void convt2_kernel(
    const unsigned short* __restrict__ x1, const unsigned short* __restrict__ wt2p,
    const float* __restrict__ b2, const float* __restrict__ zpage,
    unsigned short* __restrict__ x2) {
  __shared__ unsigned short At[8*6*34*8];   // 26.1KB
  int tid = threadIdx.x;
  int p = tid>>6, py=(tid>>7)&1, px=(tid>>6)&1;
  int lane = tid&63, xi = lane&31, half = lane>>5, ocl = lane&31;
  int bl = blockIdx.z;
  int Y0 = blockIdx.y*4, X0 = blockIdx.x*32;

  f32x16 acc[4][2];
  #pragma unroll
  for (int g=0;g<2;++g){
    float bv = b2[g*32+ocl];
    #pragma unroll
    for (int yr=0;yr<4;++yr){
      #pragma unroll
      for (int r=0;r<16;++r) acc[yr][g][r]=bv;
    }
  }

  for (int m=0;m<2;++m) {
    __syncthreads();
    for (int s = tid; s < 1632; s += 256) {
      int t = (s*1928)>>16;                 // s/34
      int c = s - t*34;
      int k8 = (t*43)>>8;                   // t/6
      int r = t - k8*6;
      int hg = Y0-1+r, wg = X0-1+c;
      const unsigned short* src =
          (hg>=0 && hg<128 && wg>=0 && wg<128)
              ? x1 + ((((size_t)bl*16 + m*8 + k8)*128 + hg)*128 + wg)*8
              : (const unsigned short*)zpage;
      *(bf16x8*)&At[s*8] = *(const bf16x8*)src;
    }
    __syncthreads();

    #pragma unroll
    for (int c16=0;c16<4;++c16) {
      #pragma unroll
      for (int t=0;t<4;++t) {
        int j=t>>1, kx=t&1;
        int col = xi+px+kx;
        int rb = (c16*2+half)*6 + py + j;
        bf16x8 a0 = *(const bf16x8*)&At[((rb+0)*34+col)*8];
        bf16x8 a1 = *(const bf16x8*)&At[((rb+1)*34+col)*8];
        bf16x8 a2 = *(const bf16x8*)&At[((rb+2)*34+col)*8];
        bf16x8 a3 = *(const bf16x8*)&At[((rb+3)*34+col)*8];
        const unsigned short* wb = wt2p + ((size_t)(((((p*2+m)*4+c16)*4+t)*2))*64 + lane)*8;
        bf16x8 bf0 = *(const bf16x8*)wb;
        bf16x8 bf1 = *(const bf16x8*)(wb + 512);
        acc[0][0]=mfma32(a0,bf0,acc[0][0]); acc[1][0]=mfma32(a1,bf0,acc[1][0]);
        acc[2][0]=mfma32(a2,bf0,acc[2][0]); acc[3][0]=mfma32(a3,bf0,acc[3][0]);
        acc[0][1]=mfma32(a0,bf1,acc[0][1]); acc[1][1]=mfma32(a1,bf1,acc[1][1]);
        acc[2][1]=mfma32(a2,bf1,acc[2][1]); acc[3][1]=mfma32(a3,bf1,acc[3][1]);
      }
    }
  }

  #pragma unroll
  for (int yr=0;yr<4;++yr) {
    int Y = 2*(Y0+yr)+py;
    #pragma unroll
    for (int g=0;g<2;++g) {
      int oc = g*32 + ocl, cg = oc>>3, o8 = oc&7;
      unsigned short* dst = x2 + ((((size_t)bl*8 + cg)*256 + Y)*256 + (2*X0+px))*8 + o8;
      #pragma unroll
      for (int r=0;r<16;++r) {
        int xo = (r&3) + 8*(r>>2) + 4*half;
        dst[(size_t)xo*16] = f2bf(fmaxf(acc[yr][g][r], 0.f));
      }
    }
  }
}

// ---------------- conv3 3x3 64->3(+13 pad) + sigmoid, MFMA 16x16x32 --------
// in: x2 [bl][cg8][256][256][8]
__global__ __launch_bounds__(256) void conv3_kernel(
    const unsigned short* __restrict__ x2, const unsigned short* __restrict__ w3p,
    const float* __restrict__ b3, const float* __restrict__ zpage,
    float* __restrict__ out, int b0) {
  __shared__ unsigned short Xt[4*6*66*8];   // 25.3KB
  int tid = threadIdx.x, w = tid>>6, lane = tid&63;
  int xi = lane&15, k8A = (lane>>4)&3, oc = lane&15;
  int bl = blockIdx.z, b = b0 + bl;
  int y0 = blockIdx.y*4, x0 = blockIdx.x*64;
  int y = y0 + w;

  f32x4 acc[4];
  float bv = (oc<3) ? b3[oc] : 0.f;
  #pragma unroll
  for (int mt=0;mt<4;++mt){ acc[mt][0]=bv; acc[mt][1]=bv; acc[mt][2]=bv; acc[mt][3]=bv; }

  for (int c=0;c<2;++c) {
    __syncthreads();
    for (int s = tid; s < 1584; s += 256) {
      int t = (s*993)>>16;                  // s/66
      int cc = s - t*66;
      int k8 = (t*43)>>8;                   // t/6
      int r = t - k8*6;
      int rf = y0-1+r, cf = x0-1+cc;
      const unsigned short* src =
          (rf>=0 && rf<256 && cf>=0 && cf<256)
              ? x2 + ((((size_t)bl*8 + c*4 + k8)*256 + rf)*256 + cf)*8
              : (const unsigned short*)zpage;
      *(bf16x8*)&Xt[s*8] = *(const bf16x8*)src;
    }
    __syncthreads();

    #pragma unroll
    for (int t=0;t<9;++t) {
      int dy = t/3, dx = t - 3*dy;
      bf16x8 bf = *(const bf16x8*)(w3p + ((size_t)(t*2+c)*64 + lane)*8);
      #pragma unroll
      for (int mt=0;mt<4;++mt) {
        bf16x8 a = *(const bf16x8*)&Xt[((size_t)(k8A*6 + (w+dy))*66 + (mt*16 + xi + dx))*8];
        acc[mt] = mfma16(a, bf, acc[mt]);
      }
    }
  }

  if (oc < 3) {
    #pragma unroll
    for (int mt=0;mt<4;++mt) {
      f32x4 v;
      #pragma unroll
      for (int r=0;r<4;++r) v[r] = 1.f/(1.f + __expf(-acc[mt][r]));
      int x = x0 + mt*16 + ((lane>>4)&3)*4;
      *(f32x4*)(out + (((size_t)b*3 + oc)*256 + y)*256 + x) = v;
    }
  }
}

// ---------------------------------------------------------------------------
extern "C" void kernel_launch(void* const* d_in, const int* in_sizes, int n_in,
                              void* d_out, int out_size, void* d_ws, size_t ws_size,
                              hipStream_t stream) {
  const float* z  = (const float*)d_in[0];
  const float* cb = (const float*)d_in[1];
  const float* w1 = (const float*)d_in[2];
  const float* b1 = (const float*)d_in[3];
  const float* w2 = (const float*)d_in[4];
  const float* b2 = (const float*)d_in[5];
  const float* w3 = (const float*)d_in[6];
  const float* b3 = (const float*)d_in[7];
  float* out = (float*)d_out;

  char* ws = (char*)d_ws;
  size_t off = 0;
  auto alloc = [&](size_t bytes) -> void* {
    void* p = (void*)(ws + off);
    off += (bytes + 255) & ~(size_t)255;
    return p;
  };
  double* cb64         = (double*)alloc((size_t)K_*C_*8);
  double* e2           = (double*)alloc((size_t)K_*8);
  float*  zpage        = (float*)alloc(256);
  unsigned short* cbph = (unsigned short*)alloc((size_t)K_*C_*2);
  unsigned short* cbpl = (unsigned short*)alloc((size_t)K_*C_*2);
  float*  e2h          = (float*)alloc((size_t)K_*4);
  int*    cnt          = (int*)alloc(256);
  int*    list         = (int*)alloc((size_t)NPOS*4);
  unsigned short* zth  = (unsigned short*)alloc((size_t)NPOS*C_*2);
  unsigned short* ztl  = (unsigned short*)alloc((size_t)NPOS*C_*2);
  unsigned short* wt1p = (unsigned short*)alloc((size_t)65536*2);
  unsigned short* wt2p = (unsigned short*)alloc((size_t)131072*2);
  unsigned short* w3p  = (unsigned short*)alloc((size_t)9216*2);
  unsigned short* q    = (unsigned short*)alloc((size_t)NPOS*C_*2);
  size_t fixed = off;

  // per-batch: x1 16*128*128*8 bf16 (4.19MB) + x2 8*256*256*8 bf16 (8.39MB)
  size_t per_b = ((size_t)16*128*128*8 + (size_t)8*256*256*8) * 2;
  long long avail = (long long)ws_size - (long long)fixed;
  int chunk = (avail >= (long long)per_b) ? (int)(avail / (long long)per_b) : 1;
  if (chunk > B_) chunk = B_;
  unsigned short* x1 = (unsigned short*)alloc((size_t)chunk*16*128*128*8*2);
  unsigned short* x2 = (unsigned short*)alloc((size_t)chunk*8*256*256*8*2);

  prep_kernel<<<512, 256, 0, stream>>>(cb, w1, w2, w3, cb64, e2, cbph, cbpl,
                                       e2h, wt1p, wt2p, w3p, zpage, cnt);
  zprep_kernel<<<512, 256, 0, stream>>>(z, zth, ztl);
  quantm_kernel<<<1024, 256, 0, stream>>>(zth, ztl, cbph, cbpl, e2h, cb,
                                          q, cnt, list);
  refine_kernel<<<256, 256, 0, stream>>>(cnt, list, z, cb64, e2, cb, q);

  for (int b0 = 0; b0 < B_; b0 += chunk) {
    int nb = (B_ - b0 < chunk) ? (B_ - b0) : chunk;
    convt1_kernel<<<dim3(2,32,nb), 256, 0, stream>>>(q, wt1p, b1, zpage, x1, b0);
    convt2_kernel<<<dim3(4,32,nb), 256, 0, stream>>>(x1, wt2p, b2, zpage, x2);
    conv3_kernel <<<dim3(4,64,nb), 256, 0, stream>>>(x2, w3p, b3, zpage, out, b0);
  }
}

// Round 6
// 523.763 us; speedup vs baseline: 5.7475x; 1.3311x over previous
//
#include <hip/hip_runtime.h>
#include <hip/hip_bf16.h>

// ---------------------------------------------------------------------------
// VQ-VAE forward, MFMA edition, round 6.
//   convt2 rebuilt: 512-thread / 8-wave blocks (4 parity x 2 y-half), each
//   wave acc[2][2] (64 VGPR) -> <=128 VGPR -> 4 waves/SIMD (2x occupancy).
//   Staging via async global_load_lds (width 16), double-buffered IC-halves.
//   Everything else unchanged from round 5.
// ---------------------------------------------------------------------------

typedef __attribute__((ext_vector_type(8)))  short  bf16x8;
typedef __attribute__((ext_vector_type(4)))  float  f32x4;
typedef __attribute__((ext_vector_type(16))) float  f32x16;

static constexpr int B_=32, C_=32, H_=64, W_=64, K_=1024;
static constexpr int NPOS = B_*H_*W_;      // 131072

__device__ __forceinline__ unsigned short f2bf(float f){
  unsigned u = __float_as_uint(f);
  u = u + 0x7FFFu + ((u>>16)&1u);        // round-to-nearest-even
  return (unsigned short)(u>>16);
}
__device__ __forceinline__ float bf2f(unsigned short h){
  return __uint_as_float(((unsigned)h)<<16);
}
__device__ __forceinline__ f32x16 mfma32(bf16x8 a, bf16x8 b, f32x16 c){
  return __builtin_amdgcn_mfma_f32_32x32x16_bf16(a,b,c,0,0,0);
}
__device__ __forceinline__ f32x4 mfma16(bf16x8 a, bf16x8 b, f32x4 c){
  return __builtin_amdgcn_mfma_f32_16x16x32_bf16(a,b,c,0,0,0);
}
// async global->LDS, 16B per lane; LDS dest = wave-uniform base + lane*16
__device__ __forceinline__ void gload16(const void* g, void* l){
  __builtin_amdgcn_global_load_lds(
      (const __attribute__((address_space(1))) void*)(unsigned long long)g,
      (__attribute__((address_space(3))) void*)(unsigned)(unsigned long long)l,
      16, 0, 0);
}

// ---------------- prep: f64 codebook, e2, bf16x2 codebook, weight prepack --
__global__ __launch_bounds__(256) void prep_kernel(
    const float* __restrict__ cb, const float* __restrict__ w1,
    const float* __restrict__ w2, const float* __restrict__ w3,
    double* __restrict__ cb64, double* __restrict__ e2,
    unsigned short* __restrict__ cbp_hi, unsigned short* __restrict__ cbp_lo,
    float* __restrict__ e2h,
    unsigned short* __restrict__ wt1p, unsigned short* __restrict__ wt2p,
    unsigned short* __restrict__ w3p, float* __restrict__ zpage,
    int* __restrict__ cnt) {
  int idx = blockIdx.x*256 + threadIdx.x;
  if (idx == 0) cnt[0] = 0;
  if (idx < 64) zpage[idx] = 0.f;
  if (idx < K_*C_) {
    float v = cb[idx];
    cb64[idx] = (double)v;
    unsigned short h = f2bf(v);
    cbp_hi[idx] = h;
    cbp_lo[idx] = f2bf(v - bf2f(h));
  }
  if (idx < K_) {
    double s = 0.0;
    #pragma unroll
    for (int c=0;c<C_;++c){ double v=(double)cb[idx*C_+c]; s+=v*v; }
    e2[idx] = s;
    e2h[idx] = -0.5f * (float)s;
  }
  if (idx < 65536) {  // wt1p  [p][c2][t4][g4][lane64][e8]
    int e=idx&7, lane=(idx>>3)&63, g=(idx>>9)&3, t=(idx>>11)&3, c=(idx>>13)&1, p=idx>>14;
    int ic = c*16 + (lane>>5)*8 + e;
    int oc = g*32 + (lane&31);
    int ky = 2*(t>>1) + (p>>1), kx = 2*(t&1) + (p&1);
    wt1p[idx] = f2bf(w1[((ic*128+oc)*4+ky)*4+kx]);
  }
  if (idx < 131072) { // wt2p  [p][m2][c4][t4][g2][lane64][e8]
    int e=idx&7, lane=(idx>>3)&63, g=(idx>>9)&1, t=(idx>>10)&3, c=(idx>>12)&3, m=(idx>>14)&1, p=idx>>15;
    int ic = m*64 + c*16 + (lane>>5)*8 + e;
    int oc = g*32 + (lane&31);
    int ky = 2*(t>>1) + (p>>1), kx = 2*(t&1) + (p&1);
    wt2p[idx] = f2bf(w2[((ic*64+oc)*4+ky)*4+kx]);
  }
  if (idx < 9216) {   // w3p  [t9][c2][lane64][e8]
    int e=idx&7, lane=(idx>>3)&63, c=(idx>>9)&1, t=idx>>10;
    int ic = c*32 + ((lane>>4)&3)*8 + e;
    int oc = lane&15;
    int dy = t/3, dx = t - 3*dy;
    w3p[idx] = (oc<3) ? f2bf(w3[((oc*64+ic)*3+dy)*3+dx]) : (unsigned short)0;
  }
}

// ---------------- z transpose + bf16x2 split: zt[n][c] --------------------
__global__ __launch_bounds__(256) void zprep_kernel(
    const float* __restrict__ z, unsigned short* __restrict__ zth,
    unsigned short* __restrict__ ztl) {
  int n = blockIdx.x*256 + threadIdx.x;     // 0..131071
  int b = n >> 12, hw = n & 4095;
  const float* zp = z + (((size_t)b*C_) << 12) + hw;
  unsigned short th[C_], tl[C_];
  #pragma unroll
  for (int c=0;c<C_;++c) {
    float v = zp[(size_t)c<<12];
    unsigned short h = f2bf(v);
    th[c] = h;
    tl[c] = f2bf(v - bf2f(h));
  }
  bf16x8* dh = (bf16x8*)(zth + (size_t)n*C_);
  bf16x8* dl = (bf16x8*)(ztl + (size_t)n*C_);
  #pragma unroll
  for (int v=0;v<4;++v){ dh[v]=((bf16x8*)th)[v]; dl[v]=((bf16x8*)tl)[v]; }
}

// ---------------- MFMA argmin screening ------------------------------------
__global__ __launch_bounds__(256) void quantm_kernel(
    const unsigned short* __restrict__ zth, const unsigned short* __restrict__ ztl,
    const unsigned short* __restrict__ cbp_hi, const unsigned short* __restrict__ cbp_lo,
    const float* __restrict__ e2h, const float* __restrict__ cb,
    unsigned short* __restrict__ q, int* __restrict__ cnt, int* __restrict__ list) {
  __shared__ bf16x8 ch[1024], cl[1024];     // 16KB + 16KB
  __shared__ float  el[256];
  int tid = threadIdx.x, lane = tid&63, wv = tid>>6;
  int m0 = blockIdx.x*128 + wv*32;
  int colL = lane&15, g = lane>>4;

  bf16x8 ah[2], al[2];
  #pragma unroll
  for (int mt=0;mt<2;++mt) {
    int pos = m0 + mt*16 + colL;
    ah[mt] = *(const bf16x8*)(zth + (size_t)pos*C_ + g*8);
    al[mt] = *(const bf16x8*)(ztl + (size_t)pos*C_ + g*8);
  }

  float b1[2][4], b2[2][4]; int i1[2][4];
  #pragma unroll
  for (int mt=0;mt<2;++mt)
    #pragma unroll
    for (int r=0;r<4;++r){ b1[mt][r]=-3e38f; b2[mt][r]=-3e38f; i1[mt][r]=0; }

  for (int cb0 = 0; cb0 < K_; cb0 += 256) {
    __syncthreads();
    {
      const bf16x8* sh = (const bf16x8*)cbp_hi + cb0*4;
      const bf16x8* sl = (const bf16x8*)cbp_lo + cb0*4;
      #pragma unroll
      for (int v=0;v<4;++v){ ch[tid + v*256] = sh[tid + v*256];
                             cl[tid + v*256] = sl[tid + v*256]; }
      el[tid] = e2h[cb0 + tid];
    }
    __syncthreads();
    #pragma unroll
    for (int nt=0; nt<16; ++nt) {
      int cloc = nt*16 + colL;
      float ei = el[cloc];
      bf16x8 bh = ch[cloc*4 + g];
      bf16x8 bl = cl[cloc*4 + g];
      int nidx = cb0 + cloc;
      #pragma unroll
      for (int mt=0;mt<2;++mt) {
        f32x4 acc = {ei, ei, ei, ei};
        acc = mfma16(al[mt], bh, acc);
        acc = mfma16(ah[mt], bl, acc);
        acc = mfma16(ah[mt], bh, acc);
        #pragma unroll
        for (int r=0;r<4;++r) {
          float s = acc[r];
          b2[mt][r] = fmaxf(b2[mt][r], fminf(s, b1[mt][r]));
          if (s > b1[mt][r]) { b1[mt][r] = s; i1[mt][r] = nidx; }
        }
      }
    }
  }

  #pragma unroll
  for (int mask=1; mask<16; mask<<=1) {
    #pragma unroll
    for (int mt=0;mt<2;++mt)
      #pragma unroll
      for (int r=0;r<4;++r) {
        float o1 = __shfl_xor(b1[mt][r], mask);
        float o2 = __shfl_xor(b2[mt][r], mask);
        int   oi = __shfl_xor(i1[mt][r], mask);
        float nb2 = fmaxf(fminf(b1[mt][r], o1), fmaxf(b2[mt][r], o2));
        if (o1 > b1[mt][r]) { b1[mt][r] = o1; i1[mt][r] = oi; }
        b2[mt][r] = nb2;
      }
  }

  #pragma unroll
  for (int mt=0;mt<2;++mt)
    #pragma unroll
    for (int r=0;r<4;++r) {
      int m = m0 + mt*16 + g*4 + r;
      int idx = i1[mt][r];
      unsigned h0 = f2bf(cb[idx*C_ + 2*colL]);
      unsigned h1 = f2bf(cb[idx*C_ + 2*colL + 1]);
      ((unsigned*)q)[(((size_t)(colL>>2))*NPOS + m)*4 + (colL&3)] = h0 | (h1<<16);
      if (colL == 0 && (b1[mt][r] - b2[mt][r]) < 0.02f) {
        int slot = atomicAdd(cnt, 1);
        list[slot] = m;
      }
    }
}

// ---------------- exact f64 refine, one wave per position ------------------
__global__ __launch_bounds__(256) void refine_kernel(
    const int* __restrict__ cnt, const int* __restrict__ list,
    const float* __restrict__ z, const double* __restrict__ cb64,
    const double* __restrict__ e2, const float* __restrict__ cb,
    unsigned short* __restrict__ q) {
  int lane = threadIdx.x & 63;
  int wv = (blockIdx.x*256 + threadIdx.x) >> 6;
  int n_ref = cnt[0];
  for (int w = wv; w < n_ref; w += 1024) {
    int m = list[w];
    int b = m >> 12, hw = m & 4095;
    const float* zp = z + (((size_t)b*C_) << 12) + hw;
    double zr[C_];
    #pragma unroll
    for (int c=0;c<C_;++c) zr[c] = (double)zp[(size_t)c<<12];
    double best = -1e300; int bi = 0;
    for (int kk=0; kk<16; ++kk) {
      int k = kk*64 + lane;
      const double* e = cb64 + k*C_;
      double a0=0,a1=0,a2=0,a3=0;
      #pragma unroll
      for (int c=0;c<C_;c+=4) {
        a0 += zr[c  ]*e[c  ]; a1 += zr[c+1]*e[c+1];
        a2 += zr[c+2]*e[c+2]; a3 += zr[c+3]*e[c+3];
      }
      double s = 2.0*((a0+a1)+(a2+a3)) - e2[k];
      if (s > best) { best = s; bi = k; }
    }
    #pragma unroll
    for (int mask=1; mask<64; mask<<=1) {
      double ob = __shfl_xor(best, mask);
      int    oi = __shfl_xor(bi, mask);
      if (ob > best || (ob == best && oi < bi)) { best = ob; bi = oi; }
    }
    if (lane < 16) {
      unsigned h0 = f2bf(cb[bi*C_ + 2*lane]);
      unsigned h1 = f2bf(cb[bi*C_ + 2*lane + 1]);
      ((unsigned*)q)[(((size_t)(lane>>2))*NPOS + m)*4 + (lane&3)] = h0 | (h1<<16);
    }
  }
}

// ---------------- convT1: 32->128, parity implicit GEMM --------------------
// in: q [cg4][n][8]; out: x1 [bl][cg16][128][128][8]
__global__ __launch_bounds__(256) void convt1_kernel(
    const unsigned short* __restrict__ q, const unsigned short* __restrict__ wt1p,
    const float* __restrict__ b1, const float* __restrict__ zpage,
    unsigned short* __restrict__ x1, int b0) {
  __shared__ unsigned short At[4*4*34*8];   // [k8][r][c][8] 8.5KB
  int tid = threadIdx.x;
  int p = tid>>6, py=(tid>>7)&1, px=(tid>>6)&1;
  int lane = tid&63, xi = lane&31, half = lane>>5, ocl = lane&31;
  int bl = blockIdx.z, b = b0 + bl;
  int Y0 = blockIdx.y*2, X0 = blockIdx.x*32;

  for (int s = tid; s < 544; s += 256) {
    int t = (s*1928)>>16;                   // s/34
    int c = s - t*34;
    int r = t & 3, k8 = t >> 2;
    int hg = Y0-1+r, wg = X0-1+c;
    const unsigned short* src =
        (hg>=0 && hg<64 && wg>=0 && wg<64)
            ? q + ((size_t)k8*NPOS + ((b<<12) + hg*64 + wg))*8
            : (const unsigned short*)zpage;
    *(bf16x8*)&At[s*8] = *(const bf16x8*)src;
  }
  __syncthreads();

  f32x16 acc[2][4];
  #pragma unroll
  for (int g=0;g<4;++g){
    float bv = b1[g*32+ocl];
    #pragma unroll
    for (int yr=0;yr<2;++yr){
      #pragma unroll
      for (int r=0;r<16;++r) acc[yr][g][r]=bv;
    }
  }

  #pragma unroll
  for (int c16=0;c16<2;++c16) {
    #pragma unroll
    for (int t=0;t<4;++t) {
      int j=t>>1, kx=t&1;
      int col = xi+px+kx;
      int rb = (c16*2+half)*4 + py + j;
      bf16x8 a0 = *(const bf16x8*)&At[((rb+0)*34+col)*8];
      bf16x8 a1 = *(const bf16x8*)&At[((rb+1)*34+col)*8];
      const unsigned short* wb = wt1p + ((size_t)(((p*2+c16)*4+t)*4)*64 + lane)*8;
      #pragma unroll
      for (int g=0;g<4;++g) {
        bf16x8 bf = *(const bf16x8*)(wb + g*512);
        acc[0][g] = mfma32(a0, bf, acc[0][g]);
        acc[1][g] = mfma32(a1, bf, acc[1][g]);
      }
    }
  }

  #pragma unroll
  for (int yr=0;yr<2;++yr) {
    int Y = 2*(Y0+yr)+py;
    #pragma unroll
    for (int g=0;g<4;++g) {
      int oc = g*32 + ocl, cg = oc>>3, o8 = oc&7;
      unsigned short* dst = x1 + ((((size_t)bl*16 + cg)*128 + Y)*128 + (2*X0+px))*8 + o8;
      #pragma unroll
      for (int r=0;r<16;++r) {
        int xo = (r&3) + 8*(r>>2) + 4*half;
        dst[(size_t)xo*16] = f2bf(fmaxf(acc[yr][g][r], 0.f));
      }
    }
  }
}

// ---------------- convT2: 128->64, 8-wave parity x y-half implicit GEMM ----
// in: x1 [bl][cg16][128][128][8]; out: x2 [bl][cg8][256][256][8]
// waves: p = wv>>1 (parity), yh = wv&1 (y half). acc[2 yr][2 ocg].
// LDS double-buffered per IC-half (m): stage m0, sync, stage m1 async,
// compute m0, sync, compute m1.
__global__ __launch_bounds__(512, 4) void convt2_kernel(
    const unsigned short* __restrict__ x1, const unsigned short* __restrict__ wt2p,
    const float* __restrict__ b2, const float* __restrict__ zpage,
    unsigned short* __restrict__ x2) {
  __shared__ unsigned short At[2][1664*8];  // 2 x 26.6KB (slots padded 1632->1664)
  int tid = threadIdx.x;
  int wv = __builtin_amdgcn_readfirstlane(tid>>6);
  int lane = tid&63;
  int p = wv>>1, yh = wv&1;
  int py = p>>1, px = p&1;
  int xi = lane&31, half = lane>>5, ocl = lane&31;
  int bl = blockIdx.z;
  int Y0 = blockIdx.y*4, X0 = blockIdx.x*32;

  // ---- stage IC-half m into buffer buf (async, 16B/lane) ----
  auto stage = [&](int m, int buf) {
    const unsigned short* xsrc = x1 + ((size_t)bl*16 + m*8)*128*128*8;
    #pragma unroll
    for (int it = 0; it < 4; ++it) {
      int sbase = it*512 + wv*64;           // wave-uniform
      if (sbase < 1664) {
        int s = sbase + lane;
        int t = (s*1928)>>16;               // s/34
        int c = s - t*34;
        int k8 = (t*43)>>8;                 // t/6
        int r = t - k8*6;
        int hg = Y0-1+r, wg = X0-1+c;
        bool v = (s < 1632) && hg>=0 && hg<128 && wg>=0 && wg<128;
        const void* src = v ? (const void*)(xsrc + (((size_t)k8*128 + hg)*128 + wg)*8)
                            : (const void*)zpage;
        gload16(src, (void*)&At[buf][sbase*8]);
      }
    }
  };

  f32x16 acc[2][2];
  #pragma unroll
  for (int g=0;g<2;++g){
    float bv = b2[g*32+ocl];
    #pragma unroll
    for (int yr=0;yr<2;++yr){
      #pragma unroll
      for (int r=0;r<16;++r) acc[yr][g][r]=bv;
    }
  }

  stage(0, 0);
  __syncthreads();          // vmcnt(0) drain + barrier: buf0 ready
  stage(1, 1);              // async, hides under compute(m=0)

  #pragma unroll
  for (int m=0;m<2;++m) {
    if (m == 1) __syncthreads();   // buf1 ready (vmcnt drained at barrier)
    const unsigned short* Ab = At[m];
    #pragma unroll
    for (int c16=0;c16<4;++c16) {
      #pragma unroll
      for (int t=0;t<4;++t) {
        int j=t>>1, kx=t&1;
        int col = xi+px+kx;
        int rb = (c16*2+half)*6 + py + j + yh*2;
        bf16x8 a0 = *(const bf16x8*)&Ab[((rb+0)*34+col)*8];
        bf16x8 a1 = *(const bf16x8*)&Ab[((rb+1)*34+col)*8];
        const unsigned short* wb = wt2p + ((size_t)(((((p*2+m)*4+c16)*4+t)*2))*64 + lane)*8;
        bf16x8 bf0 = *(const bf16x8*)wb;
        bf16x8 bf1 = *(const bf16x8*)(wb + 512);
        acc[0][0]=mfma32(a0,bf0,acc[0][0]); acc[1][0]=mfma32(a1,bf0,acc[1][0]);
        acc[0][1]=mfma32(a0,bf1,acc[0][1]); acc[1][1]=mfma32(a1,bf1,acc[1][1]);
      }
    }
  }

  #pragma unroll
  for (int yr=0;yr<2;++yr) {
    int Y = 2*(Y0 + yh*2 + yr) + py;
    #pragma unroll
    for (int g=0;g<2;++g) {
      int oc = g*32 + ocl, cg = oc>>3, o8 = oc&7;
      unsigned short* dst = x2 + ((((size_t)bl*8 + cg)*256 + Y)*256 + (2*X0+px))*8 + o8;
      #pragma unroll
      for (int r=0;r<16;++r) {
        int xo = (r&3) + 8*(r>>2) + 4*half;
        dst[(size_t)xo*16] = f2bf(fmaxf(acc[yr][g][r], 0.f));
      }
    }
  }
}

// ---------------- conv3 3x3 64->3(+13 pad) + sigmoid, MFMA 16x16x32 --------
// in: x2 [bl][cg8][256][256][8]
__global__ __launch_bounds__(256) void conv3_kernel(
    const unsigned short* __restrict__ x2, const unsigned short* __restrict__ w3p,
    const float* __restrict__ b3, const float* __restrict__ zpage,
    float* __restrict__ out, int b0) {
  __shared__ unsigned short Xt[4*6*66*8];   // 25.3KB
  int tid = threadIdx.x, w = tid>>6, lane = tid&63;
  int xi = lane&15, k8A = (lane>>4)&3, oc = lane&15;
  int bl = blockIdx.z, b = b0 + bl;
  int y0 = blockIdx.y*4, x0 = blockIdx.x*64;
  int y = y0 + w;

  f32x4 acc[4];
  float bv = (oc<3) ? b3[oc] : 0.f;
  #pragma unroll
  for (int mt=0;mt<4;++mt){ acc[mt][0]=bv; acc[mt][1]=bv; acc[mt][2]=bv; acc[mt][3]=bv; }

  for (int c=0;c<2;++c) {
    __syncthreads();
    for (int s = tid; s < 1584; s += 256) {
      int t = (s*993)>>16;                  // s/66
      int cc = s - t*66;
      int k8 = (t*43)>>8;                   // t/6
      int r = t - k8*6;
      int rf = y0-1+r, cf = x0-1+cc;
      const unsigned short* src =
          (rf>=0 && rf<256 && cf>=0 && cf<256)
              ? x2 + ((((size_t)bl*8 + c*4 + k8)*256 + rf)*256 + cf)*8
              : (const unsigned short*)zpage;
      *(bf16x8*)&Xt[s*8] = *(const bf16x8*)src;
    }
    __syncthreads();

    #pragma unroll
    for (int t=0;t<9;++t) {
      int dy = t/3, dx = t - 3*dy;
      bf16x8 bf = *(const bf16x8*)(w3p + ((size_t)(t*2+c)*64 + lane)*8);
      #pragma unroll
      for (int mt=0;mt<4;++mt) {
        bf16x8 a = *(const bf16x8*)&Xt[((size_t)(k8A*6 + (w+dy))*66 + (mt*16 + xi + dx))*8];
        acc[mt] = mfma16(a, bf, acc[mt]);
      }
    }
  }

  if (oc < 3) {
    #pragma unroll
    for (int mt=0;mt<4;++mt) {
      f32x4 v;
      #pragma unroll
      for (int r=0;r<4;++r) v[r] = 1.f/(1.f + __expf(-acc[mt][r]));
      int x = x0 + mt*16 + ((lane>>4)&3)*4;
      *(f32x4*)(out + (((size_t)b*3 + oc)*256 + y)*256 + x) = v;
    }
  }
}

// ---------------------------------------------------------------------------
extern "C" void kernel_launch(void* const* d_in, const int* in_sizes, int n_in,
                              void* d_out, int out_size, void* d_ws, size_t ws_size,
                              hipStream_t stream) {
  const float* z  = (const float*)d_in[0];
  const float* cb = (const float*)d_in[1];
  const float* w1 = (const float*)d_in[2];
  const float* b1 = (const float*)d_in[3];
  const float* w2 = (const float*)d_in[4];
  const float* b2 = (const float*)d_in[5];
  const float* w3 = (const float*)d_in[6];
  const float* b3 = (const float*)d_in[7];
  float* out = (float*)d_out;

  char* ws = (char*)d_ws;
  size_t off = 0;
  auto alloc = [&](size_t bytes) -> void* {
    void* p = (void*)(ws + off);
    off += (bytes + 255) & ~(size_t)255;
    return p;
  };
  double* cb64         = (double*)alloc((size_t)K_*C_*8);
  double* e2           = (double*)alloc((size_t)K_*8);
  float*  zpage        = (float*)alloc(256);
  unsigned short* cbph = (unsigned short*)alloc((size_t)K_*C_*2);
  unsigned short* cbpl = (unsigned short*)alloc((size_t)K_*C_*2);
  float*  e2h          = (float*)alloc((size_t)K_*4);
  int*    cnt          = (int*)alloc(256);
  int*    list         = (int*)alloc((size_t)NPOS*4);
  unsigned short* zth  = (unsigned short*)alloc((size_t)NPOS*C_*2);
  unsigned short* ztl  = (unsigned short*)alloc((size_t)NPOS*C_*2);
  unsigned short* wt1p = (unsigned short*)alloc((size_t)65536*2);
  unsigned short* wt2p = (unsigned short*)alloc((size_t)131072*2);
  unsigned short* w3p  = (unsigned short*)alloc((size_t)9216*2);
  unsigned short* q    = (unsigned short*)alloc((size_t)NPOS*C_*2);
  size_t fixed = off;

  // per-batch: x1 16*128*128*8 bf16 (4.19MB) + x2 8*256*256*8 bf16 (8.39MB)
  size_t per_b = ((size_t)16*128*128*8 + (size_t)8*256*256*8) * 2;
  long long avail = (long long)ws_size - (long long)fixed;
  int chunk = (avail >= (long long)per_b) ? (int)(avail / (long long)per_b) : 1;
  if (chunk > B_) chunk = B_;
  unsigned short* x1 = (unsigned short*)alloc((size_t)chunk*16*128*128*8*2);
  unsigned short* x2 = (unsigned short*)alloc((size_t)chunk*8*256*256*8*2);

  prep_kernel<<<512, 256, 0, stream>>>(cb, w1, w2, w3, cb64, e2, cbph, cbpl,
                                       e2h, wt1p, wt2p, w3p, zpage, cnt);
  zprep_kernel<<<512, 256, 0, stream>>>(z, zth, ztl);
  quantm_kernel<<<1024, 256, 0, stream>>>(zth, ztl, cbph, cbpl, e2h, cb,
                                          q, cnt, list);
  refine_kernel<<<256, 256, 0, stream>>>(cnt, list, z, cb64, e2, cb, q);

  for (int b0 = 0; b0 < B_; b0 += chunk) {
    int nb = (B_ - b0 < chunk) ? (B_ - b0) : chunk;
    convt1_kernel<<<dim3(2,32,nb), 256, 0, stream>>>(q, wt1p, b1, zpage, x1, b0);
    convt2_kernel<<<dim3(4,32,nb), 512, 0, stream>>>(x1, wt2p, b2, zpage, x2);
    conv3_kernel <<<dim3(4,64,nb), 256, 0, stream>>>(x2, w3p, b3, zpage, out, b0);
  }
}